// Round 11
// baseline (806.791 us; speedup 1.0000x reference)
//
#include <hip/hip_runtime.h>
#include <hip/hip_fp16.h>
#include <hip/hip_cooperative_groups.h>
#include <math.h>

namespace cg = cooperative_groups;

#define NN 50000
#define NE 800000
#define EPSV 1e-5f
#define BSHIFT 7
#define BSIZE 128
#define NB 391    // ceil(NN / 128)
#define CAP 3840  // slots per bucket; padded mean ~2930, sigma ~90 -> +10 sigma margin
#define NBLK 3125 // NN / 16 exactly
#define G7BLK 1563

typedef _Float16 h2f   __attribute__((ext_vector_type(2)));
typedef _Float16 f16x8 __attribute__((ext_vector_type(8)));
typedef float    f32x4 __attribute__((ext_vector_type(4)));

// ---------------- weight prep (interleaved Wa/Wb + R cat), BN fold, cursor init ----------------
__global__ __launch_bounds__(64) void prep_all_kernel(
        const float* __restrict__ W0, const float* __restrict__ R0,
        const float* __restrict__ W1, const float* __restrict__ R1,
        const float* __restrict__ W2, const float* __restrict__ R2,
        const float* __restrict__ B0, const float* __restrict__ B1,
        const float* __restrict__ G0, const float* __restrict__ BE0,
        const float* __restrict__ RM0, const float* __restrict__ RV0,
        const float* __restrict__ G1, const float* __restrict__ BE1,
        const float* __restrict__ RM1, const float* __restrict__ RV1,
        __half* __restrict__ Bf0, __half* __restrict__ Bf1, __half* __restrict__ Bf7,
        float* __restrict__ bn0, float* __restrict__ bn1,
        int* __restrict__ bcursor) {
    int lane = threadIdx.x;
    int bid = blockIdx.x;
    int c = lane & 15;
    int kbase = ((lane >> 4) << 3);
    _Float16 vals[8];
    if (bid < 12) {            // layer 0: ks=bid>>2 (0..2), nt=bid&3, K=96
        int ks = bid >> 2, nt = bid & 3;
        int n = nt * 16 + c;
#pragma unroll
        for (int j = 0; j < 8; ++j) {
            int kg = ks * 32 + kbase + j;
            float v = (kg < 64) ? W0[(kg & 1) * 2048 + (kg >> 1) * 64 + n]
                                : R0[(kg - 64) * 64 + n];
            vals[j] = (_Float16)v;
        }
        *reinterpret_cast<f16x8*>(Bf0 + ((size_t)(bid * 64 + lane)) * 8) =
            *reinterpret_cast<f16x8*>(vals);
    } else if (bid < 36) {     // layer 1: t=bid-12, ks=t>>2 (0..5), nt=t&3, K=192
        int t = bid - 12;
        int ks = t >> 2, nt = t & 3;
        int n = nt * 16 + c;
#pragma unroll
        for (int j = 0; j < 8; ++j) {
            int kg = ks * 32 + kbase + j;
            float v = (kg < 128) ? W1[(kg & 1) * 4096 + (kg >> 1) * 64 + n]
                                 : R1[(kg - 128) * 64 + n];
            vals[j] = (_Float16)v;
        }
        *reinterpret_cast<f16x8*>(Bf1 + ((size_t)(t * 64 + lane)) * 8) =
            *reinterpret_cast<f16x8*>(vals);
    } else if (bid < 40) {     // layer 2: [Wa|Wb packed, R], 2 ks x 2 nt
        int ksnt = bid - 36;   // 0..3
        int ks = ksnt >> 1, nt = ksnt & 1;
#pragma unroll
        for (int j = 0; j < 8; ++j) {
            int k = ks * 32 + kbase + j;
            float v = 0.f;
            if (nt == 0) {
                if (c < 7)                 v = W2[k * 7 + c];
                else if (c >= 8 && c < 15) v = W2[448 + k * 7 + (c - 8)];
            } else {
                if (c < 7)                 v = R2[k * 7 + c];
            }
            vals[j] = (_Float16)v;
        }
        *reinterpret_cast<f16x8*>(Bf7 + ((size_t)(ksnt * 64 + lane)) * 8) =
            *reinterpret_cast<f16x8*>(vals);
    } else if (bid == 40) {    // fold BN0
        float s = G0[lane] * rsqrtf(RV0[lane] + EPSV);
        bn0[lane] = s;
        bn0[64 + lane] = B0[lane] * s + BE0[lane] - RM0[lane] * s;
    } else if (bid == 41) {    // fold BN1
        float s = G1[lane] * rsqrtf(RV1[lane] + EPSV);
        bn1[lane] = s;
        bn1[64 + lane] = B1[lane] * s + BE1[lane] - RM1[lane] * s;
    } else {                   // bucket cursor init
        int b = (bid - 42) * 64 + lane;
        if (b < NB) bcursor[b] = b * CAP;
    }
}

// ---------------- fused: binB (blocks 0..NB-1, uint2 records) || x f32->f16 ----------------
__global__ __launch_bounds__(256) void binB_xh_kernel(
        const int* __restrict__ src, const int* __restrict__ dst,
        const float* __restrict__ attr, int* __restrict__ bcursor,
        uint2* __restrict__ es1, int E,
        const float* __restrict__ x, __half* __restrict__ xh) {
    __shared__ int hist[NB];
    __shared__ int base[NB];
    if (blockIdx.x >= NB) {    // x -> half, 8 floats/thread
        int t = (blockIdx.x - NB) * 256 + threadIdx.x;
        size_t idx = (size_t)t * 8;
        if (idx < (size_t)NN * 32) {
            float4 f0 = *reinterpret_cast<const float4*>(x + idx);
            float4 f1 = *reinterpret_cast<const float4*>(x + idx + 4);
            _Float16 v[8] = {(_Float16)f0.x, (_Float16)f0.y, (_Float16)f0.z, (_Float16)f0.w,
                             (_Float16)f1.x, (_Float16)f1.y, (_Float16)f1.z, (_Float16)f1.w};
            *reinterpret_cast<f16x8*>(xh + idx) = *reinterpret_cast<f16x8*>(v);
        }
        return;
    }
    for (int i = threadIdx.x; i < NB; i += blockDim.x) hist[i] = 0;
    __syncthreads();
    const int chunk = (E + NB - 1) / NB;   // 2046 -> <=8 edges/thread
    int e0 = blockIdx.x * chunk;
    int e1 = e0 + chunk; if (e1 > E) e1 = E;
    unsigned su[8]; unsigned char dlv[8]; short bv[8];
#pragma unroll
    for (int j = 0; j < 8; ++j) {
        int e = e0 + threadIdx.x + j * 256;
        if (e < e1) {
            int d = dst[e];
            int b = d >> BSHIFT;
            __half uh = __float2half_rn(attr[e]);
            su[j]  = ((unsigned)src[e] << 16) | (unsigned)__half_as_ushort(uh);
            dlv[j] = (unsigned char)(d & (BSIZE - 1));
            bv[j]  = (short)b;
            atomicAdd(&hist[b], 1);
        }
    }
    __syncthreads();
    for (int i = threadIdx.x; i < NB; i += blockDim.x) {
        int cnt = hist[i];
        base[i] = cnt ? atomicAdd(&bcursor[i], cnt) : 0;
        hist[i] = 0;
    }
    __syncthreads();
#pragma unroll
    for (int j = 0; j < 8; ++j) {
        int e = e0 + threadIdx.x + j * 256;
        if (e < e1) {
            int b = bv[j];
            int slot = base[b] + atomicAdd(&hist[b], 1);
            uint2 rec; rec.x = su[j]; rec.y = (unsigned)dlv[j];
            es1[slot] = rec;       // single 8B store (one cache line touch)
        }
    }
}

// ---------------- exact placement, node ranges PADDED to x16 with zero records ----------------
// rowrange[n] = { beg, (deg<<16) | padded }
__global__ __launch_bounds__(256) void placeC_kernel(const int* __restrict__ bcursor,
                                                     const uint2* __restrict__ es1,
                                                     int2* __restrict__ rowrange,
                                                     uint2* __restrict__ es8) {
    __shared__ int hist[BSIZE];
    __shared__ int stmp[BSIZE];
    __shared__ int cur[BSIZE];
    int b = blockIdx.x;
    int t = threadIdx.x;
    int bs = b * CAP;
    int be = bcursor[b];
    if (t < BSIZE) hist[t] = 0;
    __syncthreads();
    unsigned su[10]; unsigned char dlv[10];
#pragma unroll
    for (int j = 0; j < 10; ++j) {
        int i = bs + t + j * 256;
        if (i < be) {
            uint2 r = es1[i];
            su[j]  = r.x;
            dlv[j] = (unsigned char)r.y;
            atomicAdd(&hist[dlv[j]], 1);
        }
    }
    __syncthreads();
    if (t < BSIZE) {
        int v = hist[t];
        int pv = (v + 15) & ~15;     // padded length
        int incl = pv;
#pragma unroll
        for (int o = 1; o < 64; o <<= 1) {
            int nv = __shfl_up(incl, o, 64);
            if ((t & 63) >= o) incl += nv;
        }
        stmp[t] = incl;
    }
    __syncthreads();
    if (t < BSIZE) {
        int v = hist[t];
        int pv = (v + 15) & ~15;
        int excl = stmp[t] - pv + ((t >= 64) ? stmp[63] : 0);
        cur[t] = excl;
        int node = b * BSIZE + t;
        if (node < NN) {
            int2 rr; rr.x = bs + excl; rr.y = (v << 16) | pv;
            rowrange[node] = rr;
        }
    }
    __syncthreads();
#pragma unroll
    for (int j = 0; j < 10; ++j) {
        int i = bs + t + j * 256;
        if (i < be) {
            unsigned r = su[j];
            int dl = dlv[j];
            int slot = bs + atomicAdd(&cur[dl], 1);
            __half uh = __ushort_as_half((unsigned short)(r & 0xffffu));
            __half2 p = __halves2half2(__hsub(__ushort_as_half((unsigned short)0x3C00u), uh), uh);
            uint2 rec;
            rec.x = r >> 16;
            rec.y = *reinterpret_cast<unsigned*>(&p);
            es8[slot] = rec;
        }
    }
    __syncthreads();
    // fill pad slots with zero-weight records ({src=0, u2=0} contributes exactly 0)
    if (t < BSIZE) {
        int v = hist[t];
        int pv = (v + 15) & ~15;
        int start = bs + cur[t];          // cur[t] == excl + v after pass 2
        int endp  = bs + (cur[t] - v) + pv;
        uint2 z; z.x = 0u; z.y = 0u;
        for (int k = start; k < endp; ++k) es8[k] = z;
    }
}

// ================= shared device bodies (used by standalone kernels AND mega kernel) =================

// gf0 body: gather(CIN=32, 4 nodes/wave) -> ldsS(2KB swz) -> wave-0 GEMM K=96 -> h0
__device__ __forceinline__ void gf0_body(int nb, char* ldsS, int lane, int wid,
                                         const int2* __restrict__ rowrange,
                                         const uint2* __restrict__ es8,
                                         const __half* __restrict__ xh,
                                         const __half* __restrict__ Bf0,
                                         const float* __restrict__ bn,
                                         __half* __restrict__ h0) {
    const unsigned c2 = (unsigned)((lane & 31) << 1);
    const char* xb = (const char*)xh;
    int2 rr4 = rowrange[nb + wid * 4 + (lane & 3)];
#pragma unroll 1
    for (int k = 0; k < 4; ++k) {
        int row = wid * 4 + k;
        int beg  = __builtin_amdgcn_readfirstlane(__shfl(rr4.x, k, 64));
        int meta = __builtin_amdgcn_readfirstlane(__shfl(rr4.y, k, 64));
        int end = beg + (meta & 0xffff);
        float a0 = 0.f, a1 = 0.f, a2 = 0.f, a3 = 0.f;
        float a4 = 0.f, a5 = 0.f, a6 = 0.f, a7 = 0.f;
        float b0 = 0.f, b1 = 0.f, b2 = 0.f, b3 = 0.f;
        float b4 = 0.f, b5 = 0.f, b6 = 0.f, b7 = 0.f;
        int i = beg + (lane >> 5);
        for (; i + 14 < end; i += 16) {     // exact: padded multiple of 16
            uint2 q0 = es8[i];
            uint2 q1 = es8[i + 2];
            uint2 q2 = es8[i + 4];
            uint2 q3 = es8[i + 6];
            uint2 q4 = es8[i + 8];
            uint2 q5 = es8[i + 10];
            uint2 q6 = es8[i + 12];
            uint2 q7 = es8[i + 14];
            __half x0 = *(const __half*)(xb + ((q0.x << 6) | c2));
            __half x1 = *(const __half*)(xb + ((q1.x << 6) | c2));
            __half x2 = *(const __half*)(xb + ((q2.x << 6) | c2));
            __half x3 = *(const __half*)(xb + ((q3.x << 6) | c2));
            __half x4 = *(const __half*)(xb + ((q4.x << 6) | c2));
            __half x5 = *(const __half*)(xb + ((q5.x << 6) | c2));
            __half x6 = *(const __half*)(xb + ((q6.x << 6) | c2));
            __half x7 = *(const __half*)(xb + ((q7.x << 6) | c2));
            __half2 u0 = __builtin_bit_cast(__half2, q0.y);
            __half2 u1 = __builtin_bit_cast(__half2, q1.y);
            __half2 u2 = __builtin_bit_cast(__half2, q2.y);
            __half2 u3 = __builtin_bit_cast(__half2, q3.y);
            __half2 u4 = __builtin_bit_cast(__half2, q4.y);
            __half2 u5 = __builtin_bit_cast(__half2, q5.y);
            __half2 u6 = __builtin_bit_cast(__half2, q6.y);
            __half2 u7 = __builtin_bit_cast(__half2, q7.y);
            float f0 = __half2float(x0), f1 = __half2float(x1);
            float f2 = __half2float(x2), f3 = __half2float(x3);
            float f4 = __half2float(x4), f5 = __half2float(x5);
            float f6 = __half2float(x6), f7 = __half2float(x7);
            a0 = fmaf(__low2float(u0), f0, a0); b0 = fmaf(__high2float(u0), f0, b0);
            a1 = fmaf(__low2float(u1), f1, a1); b1 = fmaf(__high2float(u1), f1, b1);
            a2 = fmaf(__low2float(u2), f2, a2); b2 = fmaf(__high2float(u2), f2, b2);
            a3 = fmaf(__low2float(u3), f3, a3); b3 = fmaf(__high2float(u3), f3, b3);
            a4 = fmaf(__low2float(u4), f4, a4); b4 = fmaf(__high2float(u4), f4, b4);
            a5 = fmaf(__low2float(u5), f5, a5); b5 = fmaf(__high2float(u5), f5, b5);
            a6 = fmaf(__low2float(u6), f6, a6); b6 = fmaf(__high2float(u6), f6, b6);
            a7 = fmaf(__low2float(u7), f7, a7); b7 = fmaf(__high2float(u7), f7, b7);
        }
        float a = ((a0 + a1) + (a2 + a3)) + ((a4 + a5) + (a6 + a7));
        float b = ((b0 + b1) + (b2 + b3)) + ((b4 + b5) + (b6 + b7));
        a += __shfl_xor(a, 32);
        b += __shfl_xor(b, 32);
        float degv = (float)(meta >> 16);
        if (degv < 1.f) degv = 1.f;
        float inv = 1.f / degv;
        if (lane < 32) {
            int byte = (row * 128 + (lane & 31) * 4) ^ ((row & 7) << 4);
            *reinterpret_cast<__half2*>(ldsS + byte) = __floats2half2_rn(a * inv, b * inv);
        }
    }
    __syncthreads();
    if (wid == 0) {
        const int m0 = nb;
        f32x4 acc[4];
#pragma unroll
        for (int i = 0; i < 4; ++i) acc[i] = (f32x4){0.f, 0.f, 0.f, 0.f};
        const int rowl = lane & 15;
        const int g = lane >> 4;
        const int koff = g << 3;
        const int swz = (rowl & 7) << 4;
        const f16x8* bf = reinterpret_cast<const f16x8*>(Bf0);
        f16x8 a0v = *reinterpret_cast<const f16x8*>(ldsS + ((rowl * 128 + g * 16) ^ swz));
        f16x8 a1v = *reinterpret_cast<const f16x8*>(ldsS + ((rowl * 128 + 64 + g * 16) ^ swz));
        f16x8 a2v = *reinterpret_cast<const f16x8*>((const _Float16*)xh + (size_t)(m0 + rowl) * 32 + koff);
#pragma unroll
        for (int nt = 0; nt < 4; ++nt)
            acc[nt] = __builtin_amdgcn_mfma_f32_16x16x32_f16(a0v, bf[nt * 64 + lane], acc[nt], 0, 0, 0);
#pragma unroll
        for (int nt = 0; nt < 4; ++nt)
            acc[nt] = __builtin_amdgcn_mfma_f32_16x16x32_f16(a1v, bf[(4 + nt) * 64 + lane], acc[nt], 0, 0, 0);
#pragma unroll
        for (int nt = 0; nt < 4; ++nt)
            acc[nt] = __builtin_amdgcn_mfma_f32_16x16x32_f16(a2v, bf[(8 + nt) * 64 + lane], acc[nt], 0, 0, 0);
        const int c_lo  = lane & 15;
        const int rbase = ((lane >> 4) << 2);
#pragma unroll
        for (int nt = 0; nt < 4; ++nt) {
            int cc = nt * 16 + c_lo;
            float sc = bn[cc], sh = bn[64 + cc];
#pragma unroll
            for (int r = 0; r < 4; ++r) {
                int rw = m0 + rbase + r;
                float v = acc[nt][r] * sc + sh;
                v = v > 0.f ? v : expm1f(v);
                h0[(size_t)rw * 64 + cc] = __float2half(v);
            }
        }
    }
}

// gf1 body: gather(CIN=64, 16-deep) -> ldsS(4KB swz) -> wave-0 GEMM K=192 -> ldsH(2KB) -> GEMM7 -> Yab7H,Z7
__device__ __forceinline__ void gf1_body(int nb, char* ldsS, char* ldsH, int lane, int wid,
                                         const int2* __restrict__ rowrange,
                                         const uint2* __restrict__ es8,
                                         const __half* __restrict__ h0,
                                         const __half* __restrict__ Bf1,
                                         const __half* __restrict__ Bf7,
                                         const float* __restrict__ bn,
                                         const float* __restrict__ Bb2,
                                         __half* __restrict__ Yab7H,
                                         float* __restrict__ Z7) {
    const unsigned c2 = (unsigned)(lane << 1);
    const char* xb = (const char*)h0;
    int2 rr4 = rowrange[nb + wid * 4 + (lane & 3)];
#pragma unroll 1
    for (int k = 0; k < 4; ++k) {
        int row = wid * 4 + k;
        int beg  = __builtin_amdgcn_readfirstlane(__shfl(rr4.x, k, 64));
        int meta = __builtin_amdgcn_readfirstlane(__shfl(rr4.y, k, 64));
        int end = beg + (meta & 0xffff);
        float a0 = 0.f, a1 = 0.f, a2 = 0.f, a3 = 0.f;
        float a4 = 0.f, a5 = 0.f, a6 = 0.f, a7 = 0.f;
        float b0 = 0.f, b1 = 0.f, b2 = 0.f, b3 = 0.f;
        float b4 = 0.f, b5 = 0.f, b6 = 0.f, b7 = 0.f;
        for (int i = beg; i + 15 < end; i += 16) {   // exact: padded multiple of 16
            uint4 p0 = *reinterpret_cast<const uint4*>(es8 + i);
            uint4 p1 = *reinterpret_cast<const uint4*>(es8 + i + 2);
            uint4 p2 = *reinterpret_cast<const uint4*>(es8 + i + 4);
            uint4 p3 = *reinterpret_cast<const uint4*>(es8 + i + 6);
            uint4 p4 = *reinterpret_cast<const uint4*>(es8 + i + 8);
            uint4 p5 = *reinterpret_cast<const uint4*>(es8 + i + 10);
            uint4 p6 = *reinterpret_cast<const uint4*>(es8 + i + 12);
            uint4 p7 = *reinterpret_cast<const uint4*>(es8 + i + 14);
            __half x0 = *(const __half*)(xb + ((p0.x << 7) | c2));
            __half x1 = *(const __half*)(xb + ((p0.z << 7) | c2));
            __half x2 = *(const __half*)(xb + ((p1.x << 7) | c2));
            __half x3 = *(const __half*)(xb + ((p1.z << 7) | c2));
            __half x4 = *(const __half*)(xb + ((p2.x << 7) | c2));
            __half x5 = *(const __half*)(xb + ((p2.z << 7) | c2));
            __half x6 = *(const __half*)(xb + ((p3.x << 7) | c2));
            __half x7 = *(const __half*)(xb + ((p3.z << 7) | c2));
            __half x8 = *(const __half*)(xb + ((p4.x << 7) | c2));
            __half x9 = *(const __half*)(xb + ((p4.z << 7) | c2));
            __half xa = *(const __half*)(xb + ((p5.x << 7) | c2));
            __half xc = *(const __half*)(xb + ((p5.z << 7) | c2));
            __half xd = *(const __half*)(xb + ((p6.x << 7) | c2));
            __half xe = *(const __half*)(xb + ((p6.z << 7) | c2));
            __half xf = *(const __half*)(xb + ((p7.x << 7) | c2));
            __half xg = *(const __half*)(xb + ((p7.z << 7) | c2));
            __half2 u0 = __builtin_bit_cast(__half2, p0.y);
            __half2 u1 = __builtin_bit_cast(__half2, p0.w);
            __half2 u2 = __builtin_bit_cast(__half2, p1.y);
            __half2 u3 = __builtin_bit_cast(__half2, p1.w);
            __half2 u4 = __builtin_bit_cast(__half2, p2.y);
            __half2 u5 = __builtin_bit_cast(__half2, p2.w);
            __half2 u6 = __builtin_bit_cast(__half2, p3.y);
            __half2 u7 = __builtin_bit_cast(__half2, p3.w);
            __half2 u8 = __builtin_bit_cast(__half2, p4.y);
            __half2 u9 = __builtin_bit_cast(__half2, p4.w);
            __half2 ua = __builtin_bit_cast(__half2, p5.y);
            __half2 uc = __builtin_bit_cast(__half2, p5.w);
            __half2 ud = __builtin_bit_cast(__half2, p6.y);
            __half2 ue = __builtin_bit_cast(__half2, p6.w);
            __half2 uf = __builtin_bit_cast(__half2, p7.y);
            __half2 ug = __builtin_bit_cast(__half2, p7.w);
            float f0 = __half2float(x0), f1 = __half2float(x1);
            float f2 = __half2float(x2), f3 = __half2float(x3);
            float f4 = __half2float(x4), f5 = __half2float(x5);
            float f6 = __half2float(x6), f7 = __half2float(x7);
            float f8 = __half2float(x8), f9 = __half2float(x9);
            float fa = __half2float(xa), fc = __half2float(xc);
            float fd = __half2float(xd), fe = __half2float(xe);
            float ff = __half2float(xf), fg = __half2float(xg);
            a0 = fmaf(__low2float(u0), f0, a0); b0 = fmaf(__high2float(u0), f0, b0);
            a1 = fmaf(__low2float(u1), f1, a1); b1 = fmaf(__high2float(u1), f1, b1);
            a2 = fmaf(__low2float(u2), f2, a2); b2 = fmaf(__high2float(u2), f2, b2);
            a3 = fmaf(__low2float(u3), f3, a3); b3 = fmaf(__high2float(u3), f3, b3);
            a4 = fmaf(__low2float(u4), f4, a4); b4 = fmaf(__high2float(u4), f4, b4);
            a5 = fmaf(__low2float(u5), f5, a5); b5 = fmaf(__high2float(u5), f5, b5);
            a6 = fmaf(__low2float(u6), f6, a6); b6 = fmaf(__high2float(u6), f6, b6);
            a7 = fmaf(__low2float(u7), f7, a7); b7 = fmaf(__high2float(u7), f7, b7);
            a0 = fmaf(__low2float(u8), f8, a0); b0 = fmaf(__high2float(u8), f8, b0);
            a1 = fmaf(__low2float(u9), f9, a1); b1 = fmaf(__high2float(u9), f9, b1);
            a2 = fmaf(__low2float(ua), fa, a2); b2 = fmaf(__high2float(ua), fa, b2);
            a3 = fmaf(__low2float(uc), fc, a3); b3 = fmaf(__high2float(uc), fc, b3);
            a4 = fmaf(__low2float(ud), fd, a4); b4 = fmaf(__high2float(ud), fd, b4);
            a5 = fmaf(__low2float(ue), fe, a5); b5 = fmaf(__high2float(ue), fe, b5);
            a6 = fmaf(__low2float(uf), ff, a6); b6 = fmaf(__high2float(uf), ff, b6);
            a7 = fmaf(__low2float(ug), fg, a7); b7 = fmaf(__high2float(ug), fg, b7);
        }
        float a = ((a0 + a1) + (a2 + a3)) + ((a4 + a5) + (a6 + a7));
        float b = ((b0 + b1) + (b2 + b3)) + ((b4 + b5) + (b6 + b7));
        float degv = (float)(meta >> 16);
        if (degv < 1.f) degv = 1.f;
        float inv = 1.f / degv;
        int byte = (row * 256 + lane * 4) ^ ((row & 7) << 4);
        *reinterpret_cast<__half2*>(ldsS + byte) = __floats2half2_rn(a * inv, b * inv);
    }
    __syncthreads();
    if (wid == 0) {
        const int m0 = nb;
        f32x4 acc[4];
#pragma unroll
        for (int i = 0; i < 4; ++i) acc[i] = (f32x4){0.f, 0.f, 0.f, 0.f};
        const int rowl = lane & 15;
        const int g = lane >> 4;
        const int koff = g << 3;
        const int swz = (rowl & 7) << 4;
        const f16x8* bf = reinterpret_cast<const f16x8*>(Bf1);
        const _Float16* hp = (const _Float16*)h0 + (size_t)(m0 + rowl) * 64 + koff;
#pragma unroll
        for (int ks = 0; ks < 6; ++ks) {
            f16x8 av;
            if (ks < 4) av = *reinterpret_cast<const f16x8*>(ldsS + ((rowl * 256 + ks * 64 + g * 16) ^ swz));
            else        av = *reinterpret_cast<const f16x8*>(hp + (ks - 4) * 32);
#pragma unroll
            for (int nt = 0; nt < 4; ++nt)
                acc[nt] = __builtin_amdgcn_mfma_f32_16x16x32_f16(av, bf[(ks * 4 + nt) * 64 + lane], acc[nt], 0, 0, 0);
        }
        const int c_lo  = lane & 15;
        const int rbase = ((lane >> 4) << 2);
#pragma unroll
        for (int nt = 0; nt < 4; ++nt) {
            int cc = nt * 16 + c_lo;
            float sc = bn[cc], sh = bn[64 + cc];
#pragma unroll
            for (int r = 0; r < 4; ++r) {
                float v = acc[nt][r] * sc + sh;
                v = v > 0.f ? v : expm1f(v);
                int rl = rbase + r;
                *reinterpret_cast<__half*>(ldsH + ((rl * 128 + cc * 2) ^ ((rl & 7) << 4))) = __float2half(v);
            }
        }
        // GEMM7: K=64 from ldsH
        f32x4 acc7[2];
        acc7[0] = (f32x4){0.f, 0.f, 0.f, 0.f};
        acc7[1] = (f32x4){0.f, 0.f, 0.f, 0.f};
        const f16x8* bf7 = reinterpret_cast<const f16x8*>(Bf7);
#pragma unroll
        for (int ks = 0; ks < 2; ++ks) {
            f16x8 av = *reinterpret_cast<const f16x8*>(ldsH + ((rowl * 128 + ks * 64 + g * 16) ^ swz));
#pragma unroll
            for (int nt = 0; nt < 2; ++nt)
                acc7[nt] = __builtin_amdgcn_mfma_f32_16x16x32_f16(av, bf7[(ks * 2 + nt) * 64 + lane], acc7[nt], 0, 0, 0);
        }
#pragma unroll
        for (int r = 0; r < 4; ++r) {
            int rw = m0 + rbase + r;
            if (c_lo < 7) {
                Yab7H[((size_t)rw << 4) + 2 * c_lo] = __float2half(acc7[0][r]);
                Z7[((size_t)rw << 3) + c_lo] = acc7[1][r] + Bb2[c_lo];
            } else if (c_lo >= 8 && c_lo < 15) {
                Yab7H[((size_t)rw << 4) + 2 * (c_lo - 8) + 1] = __float2half(acc7[0][r]);
            }
        }
    }
}

// gather7 body: 8 lanes/node, 8-deep, log_softmax
__device__ __forceinline__ void g7_body(int tglob,
                                        const int2* __restrict__ rowrange,
                                        const uint2* __restrict__ es8,
                                        const __half2* __restrict__ Yab7H,
                                        const float* __restrict__ Z7,
                                        float* __restrict__ out, int n_nodes) {
    int n = tglob >> 3;
    int c = tglob & 7;
    if (n >= n_nodes) return;
    int2 rr = rowrange[n];
    int beg = rr.x;
    int end = beg + (rr.y & 0xffff);
    const unsigned c4 = (unsigned)(c << 2);
    const char* yb = (const char*)Yab7H;
    float acc0 = 0.f, acc1 = 0.f, acc2 = 0.f, acc3 = 0.f;
    if (c < 7) {
        for (int i = beg; i + 7 < end; i += 8) {
            uint2 q0 = es8[i];
            uint2 q1 = es8[i + 1];
            uint2 q2 = es8[i + 2];
            uint2 q3 = es8[i + 3];
            uint2 q4 = es8[i + 4];
            uint2 q5 = es8[i + 5];
            uint2 q6 = es8[i + 6];
            uint2 q7 = es8[i + 7];
            __half2 v0 = *(const __half2*)(yb + ((q0.x << 5) | c4));
            __half2 v1 = *(const __half2*)(yb + ((q1.x << 5) | c4));
            __half2 v2 = *(const __half2*)(yb + ((q2.x << 5) | c4));
            __half2 v3 = *(const __half2*)(yb + ((q3.x << 5) | c4));
            __half2 v4 = *(const __half2*)(yb + ((q4.x << 5) | c4));
            __half2 v5 = *(const __half2*)(yb + ((q5.x << 5) | c4));
            __half2 v6 = *(const __half2*)(yb + ((q6.x << 5) | c4));
            __half2 v7 = *(const __half2*)(yb + ((q7.x << 5) | c4));
            acc0 = __builtin_amdgcn_fdot2(__builtin_bit_cast(h2f, v0), __builtin_bit_cast(h2f, q0.y), acc0, false);
            acc1 = __builtin_amdgcn_fdot2(__builtin_bit_cast(h2f, v1), __builtin_bit_cast(h2f, q1.y), acc1, false);
            acc2 = __builtin_amdgcn_fdot2(__builtin_bit_cast(h2f, v2), __builtin_bit_cast(h2f, q2.y), acc2, false);
            acc3 = __builtin_amdgcn_fdot2(__builtin_bit_cast(h2f, v3), __builtin_bit_cast(h2f, q3.y), acc3, false);
            acc0 = __builtin_amdgcn_fdot2(__builtin_bit_cast(h2f, v4), __builtin_bit_cast(h2f, q4.y), acc0, false);
            acc1 = __builtin_amdgcn_fdot2(__builtin_bit_cast(h2f, v5), __builtin_bit_cast(h2f, q5.y), acc1, false);
            acc2 = __builtin_amdgcn_fdot2(__builtin_bit_cast(h2f, v6), __builtin_bit_cast(h2f, q6.y), acc2, false);
            acc3 = __builtin_amdgcn_fdot2(__builtin_bit_cast(h2f, v7), __builtin_bit_cast(h2f, q7.y), acc3, false);
        }
    }
    float acc = (acc0 + acc1) + (acc2 + acc3);
    float degv = (float)(rr.y >> 16);
    if (degv < 1.f) degv = 1.f;
    float v = (c < 7) ? (acc / degv + Z7[(n << 3) + c]) : -1e30f;
    float m = v;
#pragma unroll
    for (int o = 1; o < 8; o <<= 1) m = fmaxf(m, __shfl_xor(m, o, 8));
    float ex = (c < 7) ? expf(v - m) : 0.f;
    float ssum = ex;
#pragma unroll
    for (int o = 1; o < 8; o <<= 1) ssum += __shfl_xor(ssum, o, 8);
    if (c < 7) out[n * 7 + c] = v - m - logf(ssum);
}

// ---------------- standalone kernels (fallback path) ----------------
__global__ __launch_bounds__(256, 8) void gf0_kernel(const int2* __restrict__ rowrange,
                                                     const uint2* __restrict__ es8,
                                                     const __half* __restrict__ xh,
                                                     const __half* __restrict__ Bf0,
                                                     const float* __restrict__ bn,
                                                     __half* __restrict__ h0) {
    __shared__ __align__(16) char lds[16 * 128];
    gf0_body(blockIdx.x * 16, lds, threadIdx.x & 63, threadIdx.x >> 6,
             rowrange, es8, xh, Bf0, bn, h0);
}

__global__ __launch_bounds__(256, 8) void gf1_kernel(const int2* __restrict__ rowrange,
                                                     const uint2* __restrict__ es8,
                                                     const __half* __restrict__ h0,
                                                     const __half* __restrict__ Bf1,
                                                     const __half* __restrict__ Bf7,
                                                     const float* __restrict__ bn,
                                                     const float* __restrict__ Bb2,
                                                     __half* __restrict__ Yab7H,
                                                     float* __restrict__ Z7) {
    __shared__ __align__(16) char lds[16 * 256 + 16 * 128];
    gf1_body(blockIdx.x * 16, lds, lds + 16 * 256, threadIdx.x & 63, threadIdx.x >> 6,
             rowrange, es8, h0, Bf1, Bf7, bn, Bb2, Yab7H, Z7);
}

__global__ void gather7_final_kernel(const int2* __restrict__ rowrange,
                                     const uint2* __restrict__ es8,
                                     const __half2* __restrict__ Yab7H,
                                     const float* __restrict__ Z7,
                                     float* __restrict__ out, int n_nodes) {
    g7_body(blockIdx.x * 256 + threadIdx.x, rowrange, es8, Yab7H, Z7, out, n_nodes);
}

// ---------------- cooperative mega kernel: gf0 -> gridsync -> gf1 -> gridsync -> gather7 ----------------
__global__ __launch_bounds__(256, 8) void fused3_kernel(const int2* __restrict__ rowrange,
                                                        const uint2* __restrict__ es8,
                                                        const __half* __restrict__ xh,
                                                        const __half* __restrict__ Bf0,
                                                        const float* __restrict__ bn0,
                                                        __half* __restrict__ h0,
                                                        const __half* __restrict__ Bf1,
                                                        const __half* __restrict__ Bf7,
                                                        const float* __restrict__ bn1,
                                                        const float* __restrict__ Bb2,
                                                        __half* __restrict__ Yab7H,
                                                        float* __restrict__ Z7,
                                                        float* __restrict__ out,
                                                        int n_nodes) {
    __shared__ __align__(16) char lds[16 * 256 + 16 * 128];
    cg::grid_group grid = cg::this_grid();
    const int lane = threadIdx.x & 63;
    const int wid  = threadIdx.x >> 6;
    // phase A: layer 0 (grid-stride over 3125 16-node tiles)
    for (int bid = blockIdx.x; bid < NBLK; bid += gridDim.x) {
        gf0_body(bid * 16, lds, lane, wid, rowrange, es8, xh, Bf0, bn0, h0);
        __syncthreads();   // protect LDS reuse across iterations
    }
    grid.sync();
    // phase B: layer 1 + layer-2 transform
    for (int bid = blockIdx.x; bid < NBLK; bid += gridDim.x) {
        gf1_body(bid * 16, lds, lds + 16 * 256, lane, wid, rowrange, es8, h0, Bf1, Bf7, bn1, Bb2, Yab7H, Z7);
        __syncthreads();
    }
    grid.sync();
    // phase C: final gather + log_softmax (grid-stride over 1563 256-thread tiles)
    for (int bid = blockIdx.x; bid < G7BLK; bid += gridDim.x) {
        g7_body(bid * 256 + threadIdx.x, rowrange, es8, (const __half2*)Yab7H, Z7, out, n_nodes);
    }
}

extern "C" void kernel_launch(void* const* d_in, const int* in_sizes, int n_in,
                              void* d_out, int out_size, void* d_ws, size_t ws_size,
                              hipStream_t stream) {
    const float* x    = (const float*)d_in[0];
    const int*   ei   = (const int*)d_in[1];
    const float* attr = (const float*)d_in[2];
    const float* W0 = (const float*)d_in[3];
    const float* R0 = (const float*)d_in[4];
    const float* B0 = (const float*)d_in[5];
    const float* W1 = (const float*)d_in[6];
    const float* R1 = (const float*)d_in[7];
    const float* B1 = (const float*)d_in[8];
    const float* W2 = (const float*)d_in[9];
    const float* R2 = (const float*)d_in[10];
    const float* B2 = (const float*)d_in[11];
    const float* G0  = (const float*)d_in[12];
    const float* BE0 = (const float*)d_in[13];
    const float* RM0 = (const float*)d_in[14];
    const float* RV0 = (const float*)d_in[15];
    const float* G1  = (const float*)d_in[16];
    const float* BE1 = (const float*)d_in[17];
    const float* RM1 = (const float*)d_in[18];
    const float* RV1 = (const float*)d_in[19];

    const int* src = ei;
    const int* dst = ei + NE;
    float* out = (float*)d_out;

    // workspace layout
    char* ws = (char*)d_ws;
    size_t off = 0;
    auto alloc = [&](size_t bytes) { char* p = ws + off; off += (bytes + 255) & ~size_t(255); return p; };
    int*    bcursor  = (int*)    alloc(NB * sizeof(int));
    int2*   rowrange = (int2*)   alloc((size_t)NN * sizeof(int2));
    uint2*  es1      = (uint2*)  alloc((size_t)NB * CAP * sizeof(uint2));
    uint2*  es8      = (uint2*)  alloc((size_t)NB * CAP * sizeof(uint2));
    __half* Bf0      = (__half*) alloc((size_t)12 * 64 * 8 * sizeof(__half));
    __half* Bf1      = (__half*) alloc((size_t)24 * 64 * 8 * sizeof(__half));
    __half* Bf7      = (__half*) alloc((size_t)4 * 64 * 8 * sizeof(__half));
    float*  bn0      = (float*)  alloc(128 * sizeof(float));
    float*  bn1      = (float*)  alloc(128 * sizeof(float));
    __half* xh       = (__half*) alloc((size_t)(NN + 64) * 32 * sizeof(__half));
    __half* h0       = (__half*) alloc((size_t)(NN + 64) * 64 * sizeof(__half));
    __half* Yab7H    = (__half*) alloc((size_t)NN * 16 * sizeof(__half));
    float*  Z7       = (float*)  alloc((size_t)NN * 8 * sizeof(float));

    const int B = 256;
    const int gConv = ((NN * 32 / 8) + B - 1) / B;       // 782
    const int gPrep = 42 + (NB + 63) / 64;               // 49

    // ---- setup: weight prep (interleaved cat) + BN fold + cursor init ----
    prep_all_kernel<<<gPrep, 64, 0, stream>>>(W0, R0, W1, R1, W2, R2, B0, B1,
                                              G0, BE0, RM0, RV0, G1, BE1, RM1, RV1,
                                              Bf0, Bf1, Bf7, bn0, bn1, bcursor);

    // ---- binB (CSR binning, uint2 records) co-launched with x->half conversion ----
    binB_xh_kernel<<<NB + gConv, B, 0, stream>>>(src, dst, attr, bcursor, es1, NE, x, xh);

    // ---- exact placement (padded-to-16 node ranges) -> es8, rowrange ----
    placeC_kernel<<<NB, B, 0, stream>>>(bcursor, es1, rowrange, es8);

    // ---- layers 0..2 + softmax: cooperative mega-kernel (2 grid syncs) with fallback ----
    {
        int nn = NN;
        const int2* rrp = rowrange;
        const uint2* e8p = es8;
        const __half* xhp = xh;
        const __half* bf0p = Bf0;
        const float* bn0p = bn0;
        __half* h0p = h0;
        const __half* bf1p = Bf1;
        const __half* bf7p = Bf7;
        const float* bn1p = bn1;
        const float* b2p = B2;
        __half* yp = Yab7H;
        float* z7p = Z7;
        float* outp = out;
        void* args[] = {&rrp, &e8p, &xhp, &bf0p, &bn0p, &h0p, &bf1p, &bf7p,
                        &bn1p, &b2p, &yp, &z7p, &outp, &nn};
        hipError_t err = hipLaunchCooperativeKernel(
            reinterpret_cast<void*>(fused3_kernel), dim3(2048), dim3(B), args, 0, stream);
        if (err != hipSuccess) {
            (void)hipGetLastError();   // clear sticky error; fall back to 3-launch path
            const int gF  = NBLK;
            const int gN8 = G7BLK;
            gf0_kernel<<<gF, B, 0, stream>>>(rowrange, es8, xh, Bf0, bn0, h0);
            gf1_kernel<<<gF, B, 0, stream>>>(rowrange, es8, h0, Bf1, Bf7, bn1, B2, Yab7H, Z7);
            gather7_final_kernel<<<gN8, B, 0, stream>>>(rowrange, es8, (const __half2*)Yab7H, Z7, out, NN);
        }
    }
}

// Round 13
// 192.626 us; speedup vs baseline: 4.1884x; 4.1884x over previous
//
#include <hip/hip_runtime.h>
#include <hip/hip_fp16.h>
#include <math.h>

#define NN 50000
#define NE 800000
#define EPSV 1e-5f
#define BSHIFT 7
#define BSIZE 128
#define NB 391    // ceil(NN / 128)
#define CAP 3840  // slots per bucket; padded mean ~2930, sigma ~90 -> +10 sigma margin

typedef _Float16 h2f   __attribute__((ext_vector_type(2)));
typedef _Float16 f16x8 __attribute__((ext_vector_type(8)));
typedef float    f32x4 __attribute__((ext_vector_type(4)));

// ---------------- weight prep (interleaved Wa/Wb + R cat), BN fold, cursor init ----------------
__global__ __launch_bounds__(64) void prep_all_kernel(
        const float* __restrict__ W0, const float* __restrict__ R0,
        const float* __restrict__ W1, const float* __restrict__ R1,
        const float* __restrict__ W2, const float* __restrict__ R2,
        const float* __restrict__ B0, const float* __restrict__ B1,
        const float* __restrict__ G0, const float* __restrict__ BE0,
        const float* __restrict__ RM0, const float* __restrict__ RV0,
        const float* __restrict__ G1, const float* __restrict__ BE1,
        const float* __restrict__ RM1, const float* __restrict__ RV1,
        __half* __restrict__ Bf0, __half* __restrict__ Bf1, __half* __restrict__ Bf7,
        float* __restrict__ bn0, float* __restrict__ bn1,
        int* __restrict__ bcursor) {
    int lane = threadIdx.x;
    int bid = blockIdx.x;
    int c = lane & 15;
    int kbase = ((lane >> 4) << 3);
    _Float16 vals[8];
    if (bid < 12) {            // layer 0: ks=bid>>2 (0..2), nt=bid&3, K=96
        int ks = bid >> 2, nt = bid & 3;
        int n = nt * 16 + c;
#pragma unroll
        for (int j = 0; j < 8; ++j) {
            int kg = ks * 32 + kbase + j;
            float v = (kg < 64) ? W0[(kg & 1) * 2048 + (kg >> 1) * 64 + n]
                                : R0[(kg - 64) * 64 + n];
            vals[j] = (_Float16)v;
        }
        *reinterpret_cast<f16x8*>(Bf0 + ((size_t)(bid * 64 + lane)) * 8) =
            *reinterpret_cast<f16x8*>(vals);
    } else if (bid < 36) {     // layer 1: t=bid-12, ks=t>>2 (0..5), nt=t&3, K=192
        int t = bid - 12;
        int ks = t >> 2, nt = t & 3;
        int n = nt * 16 + c;
#pragma unroll
        for (int j = 0; j < 8; ++j) {
            int kg = ks * 32 + kbase + j;
            float v = (kg < 128) ? W1[(kg & 1) * 4096 + (kg >> 1) * 64 + n]
                                 : R1[(kg - 128) * 64 + n];
            vals[j] = (_Float16)v;
        }
        *reinterpret_cast<f16x8*>(Bf1 + ((size_t)(t * 64 + lane)) * 8) =
            *reinterpret_cast<f16x8*>(vals);
    } else if (bid < 40) {     // layer 2: [Wa|Wb packed, R], 2 ks x 2 nt
        int ksnt = bid - 36;   // 0..3
        int ks = ksnt >> 1, nt = ksnt & 1;
#pragma unroll
        for (int j = 0; j < 8; ++j) {
            int k = ks * 32 + kbase + j;
            float v = 0.f;
            if (nt == 0) {
                if (c < 7)                 v = W2[k * 7 + c];
                else if (c >= 8 && c < 15) v = W2[448 + k * 7 + (c - 8)];
            } else {
                if (c < 7)                 v = R2[k * 7 + c];
            }
            vals[j] = (_Float16)v;
        }
        *reinterpret_cast<f16x8*>(Bf7 + ((size_t)(ksnt * 64 + lane)) * 8) =
            *reinterpret_cast<f16x8*>(vals);
    } else if (bid == 40) {    // fold BN0
        float s = G0[lane] * rsqrtf(RV0[lane] + EPSV);
        bn0[lane] = s;
        bn0[64 + lane] = B0[lane] * s + BE0[lane] - RM0[lane] * s;
    } else if (bid == 41) {    // fold BN1
        float s = G1[lane] * rsqrtf(RV1[lane] + EPSV);
        bn1[lane] = s;
        bn1[64 + lane] = B1[lane] * s + BE1[lane] - RM1[lane] * s;
    } else {                   // bucket cursor init
        int b = (bid - 42) * 64 + lane;
        if (b < NB) bcursor[b] = b * CAP;
    }
}

// ---------------- fused: binB (blocks 0..NB-1, packed uint2 records) || x f32->f16 ----------------
__global__ __launch_bounds__(256) void binB_xh_kernel(
        const int* __restrict__ src, const int* __restrict__ dst,
        const float* __restrict__ attr, int* __restrict__ bcursor,
        uint2* __restrict__ es1, int E,
        const float* __restrict__ x, __half* __restrict__ xh) {
    __shared__ int hist[NB];
    __shared__ int base[NB];
    if (blockIdx.x >= NB) {    // x -> half, 8 floats/thread
        int t = (blockIdx.x - NB) * 256 + threadIdx.x;
        size_t idx = (size_t)t * 8;
        if (idx < (size_t)NN * 32) {
            float4 f0 = *reinterpret_cast<const float4*>(x + idx);
            float4 f1 = *reinterpret_cast<const float4*>(x + idx + 4);
            _Float16 v[8] = {(_Float16)f0.x, (_Float16)f0.y, (_Float16)f0.z, (_Float16)f0.w,
                             (_Float16)f1.x, (_Float16)f1.y, (_Float16)f1.z, (_Float16)f1.w};
            *reinterpret_cast<f16x8*>(xh + idx) = *reinterpret_cast<f16x8*>(v);
        }
        return;
    }
    for (int i = threadIdx.x; i < NB; i += blockDim.x) hist[i] = 0;
    __syncthreads();
    const int chunk = (E + NB - 1) / NB;   // 2046 -> <=8 edges/thread
    int e0 = blockIdx.x * chunk;
    int e1 = e0 + chunk; if (e1 > E) e1 = E;
    unsigned su[8]; unsigned char dlv[8]; short bv[8];
#pragma unroll
    for (int j = 0; j < 8; ++j) {
        int e = e0 + threadIdx.x + j * 256;
        if (e < e1) {
            int d = dst[e];
            int b = d >> BSHIFT;
            __half uh = __float2half_rn(attr[e]);
            su[j]  = ((unsigned)src[e] << 16) | (unsigned)__half_as_ushort(uh);
            dlv[j] = (unsigned char)(d & (BSIZE - 1));
            bv[j]  = (short)b;
            atomicAdd(&hist[b], 1);
        }
    }
    __syncthreads();
    for (int i = threadIdx.x; i < NB; i += blockDim.x) {
        int cnt = hist[i];
        base[i] = cnt ? atomicAdd(&bcursor[i], cnt) : 0;
        hist[i] = 0;
    }
    __syncthreads();
#pragma unroll
    for (int j = 0; j < 8; ++j) {
        int e = e0 + threadIdx.x + j * 256;
        if (e < e1) {
            int b = bv[j];
            int slot = base[b] + atomicAdd(&hist[b], 1);
            uint2 rec; rec.x = su[j]; rec.y = (unsigned)dlv[j];
            es1[slot] = rec;       // single 8B store (one cache-line touch)
        }
    }
}

// ---------------- exact placement, node ranges PADDED to x16 with zero records ----------------
// rowrange[n] = { beg, (deg<<16) | padded }
__global__ __launch_bounds__(256) void placeC_kernel(const int* __restrict__ bcursor,
                                                     const uint2* __restrict__ es1,
                                                     int2* __restrict__ rowrange,
                                                     uint2* __restrict__ es8) {
    __shared__ int hist[BSIZE];
    __shared__ int stmp[BSIZE];
    __shared__ int cur[BSIZE];
    int b = blockIdx.x;
    int t = threadIdx.x;
    int bs = b * CAP;
    int be = bcursor[b];
    if (t < BSIZE) hist[t] = 0;
    __syncthreads();
    unsigned su[10]; unsigned char dlv[10];
#pragma unroll
    for (int j = 0; j < 10; ++j) {
        int i = bs + t + j * 256;
        if (i < be) {
            uint2 r = es1[i];
            su[j]  = r.x;
            dlv[j] = (unsigned char)r.y;
            atomicAdd(&hist[dlv[j]], 1);
        }
    }
    __syncthreads();
    if (t < BSIZE) {
        int v = hist[t];
        int pv = (v + 15) & ~15;     // padded length
        int incl = pv;
#pragma unroll
        for (int o = 1; o < 64; o <<= 1) {
            int nv = __shfl_up(incl, o, 64);
            if ((t & 63) >= o) incl += nv;
        }
        stmp[t] = incl;
    }
    __syncthreads();
    if (t < BSIZE) {
        int v = hist[t];
        int pv = (v + 15) & ~15;
        int excl = stmp[t] - pv + ((t >= 64) ? stmp[63] : 0);
        cur[t] = excl;
        int node = b * BSIZE + t;
        if (node < NN) {
            int2 rr; rr.x = bs + excl; rr.y = (v << 16) | pv;
            rowrange[node] = rr;
        }
    }
    __syncthreads();
#pragma unroll
    for (int j = 0; j < 10; ++j) {
        int i = bs + t + j * 256;
        if (i < be) {
            unsigned r = su[j];
            int dl = dlv[j];
            int slot = bs + atomicAdd(&cur[dl], 1);
            __half uh = __ushort_as_half((unsigned short)(r & 0xffffu));
            __half2 p = __halves2half2(__hsub(__ushort_as_half((unsigned short)0x3C00u), uh), uh);
            uint2 rec;
            rec.x = r >> 16;
            rec.y = *reinterpret_cast<unsigned*>(&p);
            es8[slot] = rec;
        }
    }
    __syncthreads();
    // fill pad slots with zero-weight records ({src=0, u2=0} contributes exactly 0)
    if (t < BSIZE) {
        int v = hist[t];
        int pv = (v + 15) & ~15;
        int start = bs + cur[t];          // cur[t] == excl + v after pass 2
        int endp  = bs + (cur[t] - v) + pv;
        uint2 z; z.x = 0u; z.y = 0u;
        for (int k = start; k < endp; ++k) es8[k] = z;
    }
}

// ---------------- fused layer 0: gather(CIN=32, 4 nodes/wave) -> LDS -> wave-0 GEMM K=96 ----------------
// Block = 16 nodes (3125 blocks, NN = 3125*16 exactly). Rowranges preloaded (one coalesced load).
__global__ __launch_bounds__(256, 8) void gf0_kernel(const int2* __restrict__ rowrange,
                                                     const uint2* __restrict__ es8,
                                                     const __half* __restrict__ xh,
                                                     const __half* __restrict__ Bf0,
                                                     const float* __restrict__ bn,
                                                     __half* __restrict__ h0, int n_nodes) {
    __shared__ __align__(16) char ldsS[16 * 128];   // 16 rows x 64 halves, XOR-swizzled
    const int lane = threadIdx.x & 63;
    const int wid  = threadIdx.x >> 6;
    const int nb = blockIdx.x * 16;
    const unsigned c2 = (unsigned)((lane & 31) << 1);
    const char* xb = (const char*)xh;
    // preload this wave's 4 rowranges (lane&3 selects; same addr across groups -> broadcast)
    int2 rr4 = rowrange[nb + wid * 4 + (lane & 3)];
#pragma unroll 1
    for (int k = 0; k < 4; ++k) {
        int row = wid * 4 + k;
        int beg  = __builtin_amdgcn_readfirstlane(__shfl(rr4.x, k, 64));
        int meta = __builtin_amdgcn_readfirstlane(__shfl(rr4.y, k, 64));
        int end = beg + (meta & 0xffff);
        float a0 = 0.f, a1 = 0.f, a2 = 0.f, a3 = 0.f;
        float a4 = 0.f, a5 = 0.f, a6 = 0.f, a7 = 0.f;
        float b0 = 0.f, b1 = 0.f, b2 = 0.f, b3 = 0.f;
        float b4 = 0.f, b5 = 0.f, b6 = 0.f, b7 = 0.f;
        int i = beg + (lane >> 5);
        for (; i + 14 < end; i += 16) {     // exact: padded multiple of 16
            uint2 q0 = es8[i];
            uint2 q1 = es8[i + 2];
            uint2 q2 = es8[i + 4];
            uint2 q3 = es8[i + 6];
            uint2 q4 = es8[i + 8];
            uint2 q5 = es8[i + 10];
            uint2 q6 = es8[i + 12];
            uint2 q7 = es8[i + 14];
            __half x0 = *(const __half*)(xb + ((q0.x << 6) | c2));
            __half x1 = *(const __half*)(xb + ((q1.x << 6) | c2));
            __half x2 = *(const __half*)(xb + ((q2.x << 6) | c2));
            __half x3 = *(const __half*)(xb + ((q3.x << 6) | c2));
            __half x4 = *(const __half*)(xb + ((q4.x << 6) | c2));
            __half x5 = *(const __half*)(xb + ((q5.x << 6) | c2));
            __half x6 = *(const __half*)(xb + ((q6.x << 6) | c2));
            __half x7 = *(const __half*)(xb + ((q7.x << 6) | c2));
            __half2 u0 = __builtin_bit_cast(__half2, q0.y);
            __half2 u1 = __builtin_bit_cast(__half2, q1.y);
            __half2 u2 = __builtin_bit_cast(__half2, q2.y);
            __half2 u3 = __builtin_bit_cast(__half2, q3.y);
            __half2 u4 = __builtin_bit_cast(__half2, q4.y);
            __half2 u5 = __builtin_bit_cast(__half2, q5.y);
            __half2 u6 = __builtin_bit_cast(__half2, q6.y);
            __half2 u7 = __builtin_bit_cast(__half2, q7.y);
            float f0 = __half2float(x0), f1 = __half2float(x1);
            float f2 = __half2float(x2), f3 = __half2float(x3);
            float f4 = __half2float(x4), f5 = __half2float(x5);
            float f6 = __half2float(x6), f7 = __half2float(x7);
            a0 = fmaf(__low2float(u0), f0, a0); b0 = fmaf(__high2float(u0), f0, b0);
            a1 = fmaf(__low2float(u1), f1, a1); b1 = fmaf(__high2float(u1), f1, b1);
            a2 = fmaf(__low2float(u2), f2, a2); b2 = fmaf(__high2float(u2), f2, b2);
            a3 = fmaf(__low2float(u3), f3, a3); b3 = fmaf(__high2float(u3), f3, b3);
            a4 = fmaf(__low2float(u4), f4, a4); b4 = fmaf(__high2float(u4), f4, b4);
            a5 = fmaf(__low2float(u5), f5, a5); b5 = fmaf(__high2float(u5), f5, b5);
            a6 = fmaf(__low2float(u6), f6, a6); b6 = fmaf(__high2float(u6), f6, b6);
            a7 = fmaf(__low2float(u7), f7, a7); b7 = fmaf(__high2float(u7), f7, b7);
        }
        float a = ((a0 + a1) + (a2 + a3)) + ((a4 + a5) + (a6 + a7));
        float b = ((b0 + b1) + (b2 + b3)) + ((b4 + b5) + (b6 + b7));
        a += __shfl_xor(a, 32);
        b += __shfl_xor(b, 32);
        float degv = (float)(meta >> 16);
        if (degv < 1.f) degv = 1.f;
        float inv = 1.f / degv;
        if (lane < 32) {
            int byte = (row * 128 + (lane & 31) * 4) ^ ((row & 7) << 4);
            *reinterpret_cast<__half2*>(ldsS + byte) = __floats2half2_rn(a * inv, b * inv);
        }
    }
    __syncthreads();
    if (wid != 0) return;

    // ---- wave-0 GEMM: rows nb..nb+15, A=[S(LDS) | xh], K=96, N=64, BN+ELU -> h0 ----
    const int m0 = nb;
    f32x4 acc[4];
#pragma unroll
    for (int i = 0; i < 4; ++i) acc[i] = (f32x4){0.f, 0.f, 0.f, 0.f};
    const int rowl = lane & 15;
    const int g = lane >> 4;
    const int koff = g << 3;
    const int swz = (rowl & 7) << 4;
    const f16x8* bf = reinterpret_cast<const f16x8*>(Bf0);
    f16x8 a0v = *reinterpret_cast<const f16x8*>(ldsS + ((rowl * 128 + g * 16) ^ swz));
    f16x8 a1v = *reinterpret_cast<const f16x8*>(ldsS + ((rowl * 128 + 64 + g * 16) ^ swz));
    f16x8 a2v = *reinterpret_cast<const f16x8*>((const _Float16*)xh + (size_t)(m0 + rowl) * 32 + koff);
#pragma unroll
    for (int nt = 0; nt < 4; ++nt)
        acc[nt] = __builtin_amdgcn_mfma_f32_16x16x32_f16(a0v, bf[nt * 64 + lane], acc[nt], 0, 0, 0);
#pragma unroll
    for (int nt = 0; nt < 4; ++nt)
        acc[nt] = __builtin_amdgcn_mfma_f32_16x16x32_f16(a1v, bf[(4 + nt) * 64 + lane], acc[nt], 0, 0, 0);
#pragma unroll
    for (int nt = 0; nt < 4; ++nt)
        acc[nt] = __builtin_amdgcn_mfma_f32_16x16x32_f16(a2v, bf[(8 + nt) * 64 + lane], acc[nt], 0, 0, 0);
    const int c_lo  = lane & 15;
    const int rbase = ((lane >> 4) << 2);
#pragma unroll
    for (int nt = 0; nt < 4; ++nt) {
        int cc = nt * 16 + c_lo;
        float sc = bn[cc], sh = bn[64 + cc];
#pragma unroll
        for (int r = 0; r < 4; ++r) {
            int rw = m0 + rbase + r;
            float v = acc[nt][r] * sc + sh;
            v = v > 0.f ? v : expm1f(v);
            h0[(size_t)rw * 64 + cc] = __float2half(v);
        }
    }
}

// ---------------- fused layer 1+2: gather(CIN=64, 4 nodes/wave, 16-deep) -> LDS -> GEMM K=192 -> GEMM7 ----------------
__global__ __launch_bounds__(256, 8) void gf1_kernel(const int2* __restrict__ rowrange,
                                                     const uint2* __restrict__ es8,
                                                     const __half* __restrict__ h0,
                                                     const __half* __restrict__ Bf1,
                                                     const __half* __restrict__ Bf7,
                                                     const float* __restrict__ bn,
                                                     const float* __restrict__ Bb2,
                                                     __half* __restrict__ Yab7H,  // (n,8) half2{a,b}
                                                     float* __restrict__ Z7,      // (n,8)
                                                     int n_nodes) {
    __shared__ __align__(16) char ldsS[16 * 256];  // 16 rows x 128 halves (s0⋈s1), swizzled
    __shared__ __align__(16) char ldsH[16 * 128];  // 16 rows x 64 halves (h1), swizzled
    const int lane = threadIdx.x & 63;
    const int wid  = threadIdx.x >> 6;
    const int nb = blockIdx.x * 16;
    const unsigned c2 = (unsigned)(lane << 1);
    const char* xb = (const char*)h0;
    int2 rr4 = rowrange[nb + wid * 4 + (lane & 3)];
#pragma unroll 1
    for (int k = 0; k < 4; ++k) {
        int row = wid * 4 + k;
        int beg  = __builtin_amdgcn_readfirstlane(__shfl(rr4.x, k, 64));
        int meta = __builtin_amdgcn_readfirstlane(__shfl(rr4.y, k, 64));
        int end = beg + (meta & 0xffff);
        float a0 = 0.f, a1 = 0.f, a2 = 0.f, a3 = 0.f;
        float a4 = 0.f, a5 = 0.f, a6 = 0.f, a7 = 0.f;
        float b0 = 0.f, b1 = 0.f, b2 = 0.f, b3 = 0.f;
        float b4 = 0.f, b5 = 0.f, b6 = 0.f, b7 = 0.f;
        for (int i = beg; i + 15 < end; i += 16) {   // exact: padded multiple of 16
            uint4 p0 = *reinterpret_cast<const uint4*>(es8 + i);
            uint4 p1 = *reinterpret_cast<const uint4*>(es8 + i + 2);
            uint4 p2 = *reinterpret_cast<const uint4*>(es8 + i + 4);
            uint4 p3 = *reinterpret_cast<const uint4*>(es8 + i + 6);
            uint4 p4 = *reinterpret_cast<const uint4*>(es8 + i + 8);
            uint4 p5 = *reinterpret_cast<const uint4*>(es8 + i + 10);
            uint4 p6 = *reinterpret_cast<const uint4*>(es8 + i + 12);
            uint4 p7 = *reinterpret_cast<const uint4*>(es8 + i + 14);
            __half x0 = *(const __half*)(xb + ((p0.x << 7) | c2));
            __half x1 = *(const __half*)(xb + ((p0.z << 7) | c2));
            __half x2 = *(const __half*)(xb + ((p1.x << 7) | c2));
            __half x3 = *(const __half*)(xb + ((p1.z << 7) | c2));
            __half x4 = *(const __half*)(xb + ((p2.x << 7) | c2));
            __half x5 = *(const __half*)(xb + ((p2.z << 7) | c2));
            __half x6 = *(const __half*)(xb + ((p3.x << 7) | c2));
            __half x7 = *(const __half*)(xb + ((p3.z << 7) | c2));
            __half x8 = *(const __half*)(xb + ((p4.x << 7) | c2));
            __half x9 = *(const __half*)(xb + ((p4.z << 7) | c2));
            __half xa = *(const __half*)(xb + ((p5.x << 7) | c2));
            __half xc = *(const __half*)(xb + ((p5.z << 7) | c2));
            __half xd = *(const __half*)(xb + ((p6.x << 7) | c2));
            __half xe = *(const __half*)(xb + ((p6.z << 7) | c2));
            __half xf = *(const __half*)(xb + ((p7.x << 7) | c2));
            __half xg = *(const __half*)(xb + ((p7.z << 7) | c2));
            __half2 u0 = __builtin_bit_cast(__half2, p0.y);
            __half2 u1 = __builtin_bit_cast(__half2, p0.w);
            __half2 u2 = __builtin_bit_cast(__half2, p1.y);
            __half2 u3 = __builtin_bit_cast(__half2, p1.w);
            __half2 u4 = __builtin_bit_cast(__half2, p2.y);
            __half2 u5 = __builtin_bit_cast(__half2, p2.w);
            __half2 u6 = __builtin_bit_cast(__half2, p3.y);
            __half2 u7 = __builtin_bit_cast(__half2, p3.w);
            __half2 u8 = __builtin_bit_cast(__half2, p4.y);
            __half2 u9 = __builtin_bit_cast(__half2, p4.w);
            __half2 ua = __builtin_bit_cast(__half2, p5.y);
            __half2 uc = __builtin_bit_cast(__half2, p5.w);
            __half2 ud = __builtin_bit_cast(__half2, p6.y);
            __half2 ue = __builtin_bit_cast(__half2, p6.w);
            __half2 uf = __builtin_bit_cast(__half2, p7.y);
            __half2 ug = __builtin_bit_cast(__half2, p7.w);
            float f0 = __half2float(x0), f1 = __half2float(x1);
            float f2 = __half2float(x2), f3 = __half2float(x3);
            float f4 = __half2float(x4), f5 = __half2float(x5);
            float f6 = __half2float(x6), f7 = __half2float(x7);
            float f8 = __half2float(x8), f9 = __half2float(x9);
            float fa = __half2float(xa), fc = __half2float(xc);
            float fd = __half2float(xd), fe = __half2float(xe);
            float ff = __half2float(xf), fg = __half2float(xg);
            a0 = fmaf(__low2float(u0), f0, a0); b0 = fmaf(__high2float(u0), f0, b0);
            a1 = fmaf(__low2float(u1), f1, a1); b1 = fmaf(__high2float(u1), f1, b1);
            a2 = fmaf(__low2float(u2), f2, a2); b2 = fmaf(__high2float(u2), f2, b2);
            a3 = fmaf(__low2float(u3), f3, a3); b3 = fmaf(__high2float(u3), f3, b3);
            a4 = fmaf(__low2float(u4), f4, a4); b4 = fmaf(__high2float(u4), f4, b4);
            a5 = fmaf(__low2float(u5), f5, a5); b5 = fmaf(__high2float(u5), f5, b5);
            a6 = fmaf(__low2float(u6), f6, a6); b6 = fmaf(__high2float(u6), f6, b6);
            a7 = fmaf(__low2float(u7), f7, a7); b7 = fmaf(__high2float(u7), f7, b7);
            a0 = fmaf(__low2float(u8), f8, a0); b0 = fmaf(__high2float(u8), f8, b0);
            a1 = fmaf(__low2float(u9), f9, a1); b1 = fmaf(__high2float(u9), f9, b1);
            a2 = fmaf(__low2float(ua), fa, a2); b2 = fmaf(__high2float(ua), fa, b2);
            a3 = fmaf(__low2float(uc), fc, a3); b3 = fmaf(__high2float(uc), fc, b3);
            a4 = fmaf(__low2float(ud), fd, a4); b4 = fmaf(__high2float(ud), fd, b4);
            a5 = fmaf(__low2float(ue), fe, a5); b5 = fmaf(__high2float(ue), fe, b5);
            a6 = fmaf(__low2float(uf), ff, a6); b6 = fmaf(__high2float(uf), ff, b6);
            a7 = fmaf(__low2float(ug), fg, a7); b7 = fmaf(__high2float(ug), fg, b7);
        }
        float a = ((a0 + a1) + (a2 + a3)) + ((a4 + a5) + (a6 + a7));
        float b = ((b0 + b1) + (b2 + b3)) + ((b4 + b5) + (b6 + b7));
        float degv = (float)(meta >> 16);
        if (degv < 1.f) degv = 1.f;
        float inv = 1.f / degv;
        int byte = (row * 256 + lane * 4) ^ ((row & 7) << 4);
        *reinterpret_cast<__half2*>(ldsS + byte) = __floats2half2_rn(a * inv, b * inv);
    }
    __syncthreads();
    if (wid != 0) return;

    // ---- wave-0 GEMM1: K=192 ([S(LDS,128) | h0(64)]), N=64, BN+ELU -> LDS H ----
    const int m0 = nb;
    f32x4 acc[4];
#pragma unroll
    for (int i = 0; i < 4; ++i) acc[i] = (f32x4){0.f, 0.f, 0.f, 0.f};
    const int rowl = lane & 15;
    const int g = lane >> 4;
    const int koff = g << 3;
    const int swz = (rowl & 7) << 4;
    const f16x8* bf = reinterpret_cast<const f16x8*>(Bf1);
    const _Float16* hp = (const _Float16*)h0 + (size_t)(m0 + rowl) * 64 + koff;
#pragma unroll
    for (int ks = 0; ks < 6; ++ks) {
        f16x8 av;
        if (ks < 4) av = *reinterpret_cast<const f16x8*>(ldsS + ((rowl * 256 + ks * 64 + g * 16) ^ swz));
        else        av = *reinterpret_cast<const f16x8*>(hp + (ks - 4) * 32);
#pragma unroll
        for (int nt = 0; nt < 4; ++nt)
            acc[nt] = __builtin_amdgcn_mfma_f32_16x16x32_f16(av, bf[(ks * 4 + nt) * 64 + lane], acc[nt], 0, 0, 0);
    }
    const int c_lo  = lane & 15;
    const int rbase = ((lane >> 4) << 2);
#pragma unroll
    for (int nt = 0; nt < 4; ++nt) {
        int cc = nt * 16 + c_lo;
        float sc = bn[cc], sh = bn[64 + cc];
#pragma unroll
        for (int r = 0; r < 4; ++r) {
            float v = acc[nt][r] * sc + sh;
            v = v > 0.f ? v : expm1f(v);
            int rl = rbase + r;
            *reinterpret_cast<__half*>(ldsH + ((rl * 128 + cc * 2) ^ ((rl & 7) << 4))) = __float2half(v);
        }
    }

    // ---- GEMM7: K=64 from LDS H (same wave), [a|b packed | R] -> Yab7H, Z7 ----
    f32x4 acc7[2];
    acc7[0] = (f32x4){0.f, 0.f, 0.f, 0.f};
    acc7[1] = (f32x4){0.f, 0.f, 0.f, 0.f};
    const f16x8* bf7 = reinterpret_cast<const f16x8*>(Bf7);
#pragma unroll
    for (int ks = 0; ks < 2; ++ks) {
        f16x8 av = *reinterpret_cast<const f16x8*>(ldsH + ((rowl * 128 + ks * 64 + g * 16) ^ swz));
#pragma unroll
        for (int nt = 0; nt < 2; ++nt)
            acc7[nt] = __builtin_amdgcn_mfma_f32_16x16x32_f16(av, bf7[(ks * 2 + nt) * 64 + lane], acc7[nt], 0, 0, 0);
    }
#pragma unroll
    for (int r = 0; r < 4; ++r) {
        int rw = m0 + rbase + r;
        if (c_lo < 7) {
            Yab7H[((size_t)rw << 4) + 2 * c_lo] = __float2half(acc7[0][r]);
            Z7[((size_t)rw << 3) + c_lo] = acc7[1][r] + Bb2[c_lo];
        } else if (c_lo >= 8 && c_lo < 15) {
            Yab7H[((size_t)rw << 4) + 2 * (c_lo - 8) + 1] = __float2half(acc7[0][r]);
        }
    }
}

// ---------------- gather (C=7, padded 8) + log_softmax: 8 lanes/node, 8-deep, NO tail ----------------
__global__ void gather7_final_kernel(const int2* __restrict__ rowrange,
                                     const uint2* __restrict__ es8,
                                     const __half2* __restrict__ Yab7H,  // (n,8) half2{a,b}
                                     const float* __restrict__ Z7,       // (n,8)
                                     float* __restrict__ out, int n_nodes) {
    int t = blockIdx.x * blockDim.x + threadIdx.x;
    int n = t >> 3;
    int c = t & 7;
    if (n >= n_nodes) return;
    int2 rr = rowrange[n];
    int beg = rr.x;
    int end = beg + (rr.y & 0xffff);
    const unsigned c4 = (unsigned)(c << 2);
    const char* yb = (const char*)Yab7H;
    float acc0 = 0.f, acc1 = 0.f, acc2 = 0.f, acc3 = 0.f;
    if (c < 7) {
        for (int i = beg; i + 7 < end; i += 8) {   // exact: padded multiple of 16
            uint2 q0 = es8[i];
            uint2 q1 = es8[i + 1];
            uint2 q2 = es8[i + 2];
            uint2 q3 = es8[i + 3];
            uint2 q4 = es8[i + 4];
            uint2 q5 = es8[i + 5];
            uint2 q6 = es8[i + 6];
            uint2 q7 = es8[i + 7];
            __half2 v0 = *(const __half2*)(yb + ((q0.x << 5) | c4));
            __half2 v1 = *(const __half2*)(yb + ((q1.x << 5) | c4));
            __half2 v2 = *(const __half2*)(yb + ((q2.x << 5) | c4));
            __half2 v3 = *(const __half2*)(yb + ((q3.x << 5) | c4));
            __half2 v4 = *(const __half2*)(yb + ((q4.x << 5) | c4));
            __half2 v5 = *(const __half2*)(yb + ((q5.x << 5) | c4));
            __half2 v6 = *(const __half2*)(yb + ((q6.x << 5) | c4));
            __half2 v7 = *(const __half2*)(yb + ((q7.x << 5) | c4));
            acc0 = __builtin_amdgcn_fdot2(__builtin_bit_cast(h2f, v0), __builtin_bit_cast(h2f, q0.y), acc0, false);
            acc1 = __builtin_amdgcn_fdot2(__builtin_bit_cast(h2f, v1), __builtin_bit_cast(h2f, q1.y), acc1, false);
            acc2 = __builtin_amdgcn_fdot2(__builtin_bit_cast(h2f, v2), __builtin_bit_cast(h2f, q2.y), acc2, false);
            acc3 = __builtin_amdgcn_fdot2(__builtin_bit_cast(h2f, v3), __builtin_bit_cast(h2f, q3.y), acc3, false);
            acc0 = __builtin_amdgcn_fdot2(__builtin_bit_cast(h2f, v4), __builtin_bit_cast(h2f, q4.y), acc0, false);
            acc1 = __builtin_amdgcn_fdot2(__builtin_bit_cast(h2f, v5), __builtin_bit_cast(h2f, q5.y), acc1, false);
            acc2 = __builtin_amdgcn_fdot2(__builtin_bit_cast(h2f, v6), __builtin_bit_cast(h2f, q6.y), acc2, false);
            acc3 = __builtin_amdgcn_fdot2(__builtin_bit_cast(h2f, v7), __builtin_bit_cast(h2f, q7.y), acc3, false);
        }
    }
    float acc = (acc0 + acc1) + (acc2 + acc3);
    float degv = (float)(rr.y >> 16);
    if (degv < 1.f) degv = 1.f;
    float v = (c < 7) ? (acc / degv + Z7[(n << 3) + c]) : -1e30f;
    float m = v;
#pragma unroll
    for (int o = 1; o < 8; o <<= 1) m = fmaxf(m, __shfl_xor(m, o, 8));
    float ex = (c < 7) ? expf(v - m) : 0.f;
    float ssum = ex;
#pragma unroll
    for (int o = 1; o < 8; o <<= 1) ssum += __shfl_xor(ssum, o, 8);
    if (c < 7) out[n * 7 + c] = v - m - logf(ssum);
}

extern "C" void kernel_launch(void* const* d_in, const int* in_sizes, int n_in,
                              void* d_out, int out_size, void* d_ws, size_t ws_size,
                              hipStream_t stream) {
    const float* x    = (const float*)d_in[0];
    const int*   ei   = (const int*)d_in[1];
    const float* attr = (const float*)d_in[2];
    const float* W0 = (const float*)d_in[3];
    const float* R0 = (const float*)d_in[4];
    const float* B0 = (const float*)d_in[5];
    const float* W1 = (const float*)d_in[6];
    const float* R1 = (const float*)d_in[7];
    const float* B1 = (const float*)d_in[8];
    const float* W2 = (const float*)d_in[9];
    const float* R2 = (const float*)d_in[10];
    const float* B2 = (const float*)d_in[11];
    const float* G0  = (const float*)d_in[12];
    const float* BE0 = (const float*)d_in[13];
    const float* RM0 = (const float*)d_in[14];
    const float* RV0 = (const float*)d_in[15];
    const float* G1  = (const float*)d_in[16];
    const float* BE1 = (const float*)d_in[17];
    const float* RM1 = (const float*)d_in[18];
    const float* RV1 = (const float*)d_in[19];

    const int* src = ei;
    const int* dst = ei + NE;
    float* out = (float*)d_out;

    // workspace layout
    char* ws = (char*)d_ws;
    size_t off = 0;
    auto alloc = [&](size_t bytes) { char* p = ws + off; off += (bytes + 255) & ~size_t(255); return p; };
    int*    bcursor  = (int*)    alloc(NB * sizeof(int));
    int2*   rowrange = (int2*)   alloc((size_t)NN * sizeof(int2));
    uint2*  es1      = (uint2*)  alloc((size_t)NB * CAP * sizeof(uint2));
    uint2*  es8      = (uint2*)  alloc((size_t)NB * CAP * sizeof(uint2));
    __half* Bf0      = (__half*) alloc((size_t)12 * 64 * 8 * sizeof(__half));
    __half* Bf1      = (__half*) alloc((size_t)24 * 64 * 8 * sizeof(__half));
    __half* Bf7      = (__half*) alloc((size_t)4 * 64 * 8 * sizeof(__half));
    float*  bn0      = (float*)  alloc(128 * sizeof(float));
    float*  bn1      = (float*)  alloc(128 * sizeof(float));
    __half* xh       = (__half*) alloc((size_t)(NN + 64) * 32 * sizeof(__half));
    __half* h0       = (__half*) alloc((size_t)(NN + 64) * 64 * sizeof(__half));
    __half* Yab7H    = (__half*) alloc((size_t)NN * 16 * sizeof(__half));
    float*  Z7       = (float*)  alloc((size_t)NN * 8 * sizeof(float));

    const int B = 256;
    const int gF    = (NN + 15) / 16;                    // 3125: fused 16-node blocks (exact)
    const int gN8   = (NN * 8 + B - 1) / B;              // 1563
    const int gConv = ((NN * 32 / 8) + B - 1) / B;       // 782
    const int gPrep = 42 + (NB + 63) / 64;               // 49

    // ---- setup: weight prep (interleaved cat) + BN fold + cursor init ----
    prep_all_kernel<<<gPrep, 64, 0, stream>>>(W0, R0, W1, R1, W2, R2, B0, B1,
                                              G0, BE0, RM0, RV0, G1, BE1, RM1, RV1,
                                              Bf0, Bf1, Bf7, bn0, bn1, bcursor);

    // ---- binB (CSR binning, packed uint2 records) co-launched with x->half conversion ----
    binB_xh_kernel<<<NB + gConv, B, 0, stream>>>(src, dst, attr, bcursor, es1, NE, x, xh);

    // ---- exact placement (padded-to-16 node ranges) -> es8, rowrange ----
    placeC_kernel<<<NB, B, 0, stream>>>(bcursor, es1, rowrange, es8);

    // ---- layer 0: fused gather(4 nodes/wave) + wave-0 GEMM(K=96)+BN+ELU ----
    gf0_kernel<<<gF, B, 0, stream>>>(rowrange, es8, xh, Bf0, bn0, h0, NN);

    // ---- layer 1+2: fused gather(16-deep) + wave-0 GEMM(K=192)+BN+ELU -> LDS -> GEMM7(K=64) ----
    gf1_kernel<<<gF, B, 0, stream>>>(rowrange, es8, h0, Bf1, Bf7, bn1, B2, Yab7H, Z7, NN);

    // ---- final: gather C=7 + log_softmax ----
    gather7_final_kernel<<<gN8, B, 0, stream>>>(rowrange, es8, (const __half2*)Yab7H, Z7, out, NN);
}

// Round 14
// 187.908 us; speedup vs baseline: 4.2935x; 1.0251x over previous
//
#include <hip/hip_runtime.h>
#include <hip/hip_fp16.h>
#include <math.h>

#define NN 50000
#define NE 800000
#define EPSV 1e-5f
#define BSHIFT 7
#define BSIZE 128
#define NB 391    // ceil(NN / 128)
#define CAP 3840  // slots per bucket; padded mean ~2930, sigma ~90 -> +10 sigma margin

typedef _Float16 h2f   __attribute__((ext_vector_type(2)));
typedef _Float16 f16x8 __attribute__((ext_vector_type(8)));
typedef float    f32x4 __attribute__((ext_vector_type(4)));

// ---------------- weight prep (interleaved Wa/Wb + R cat), BN fold, cursor init ----------------
__global__ __launch_bounds__(64) void prep_all_kernel(
        const float* __restrict__ W0, const float* __restrict__ R0,
        const float* __restrict__ W1, const float* __restrict__ R1,
        const float* __restrict__ W2, const float* __restrict__ R2,
        const float* __restrict__ B0, const float* __restrict__ B1,
        const float* __restrict__ G0, const float* __restrict__ BE0,
        const float* __restrict__ RM0, const float* __restrict__ RV0,
        const float* __restrict__ G1, const float* __restrict__ BE1,
        const float* __restrict__ RM1, const float* __restrict__ RV1,
        __half* __restrict__ Bf0, __half* __restrict__ Bf1, __half* __restrict__ Bf7,
        float* __restrict__ bn0, float* __restrict__ bn1,
        int* __restrict__ bcursor) {
    int lane = threadIdx.x;
    int bid = blockIdx.x;
    int c = lane & 15;
    int kbase = ((lane >> 4) << 3);
    _Float16 vals[8];
    if (bid < 12) {            // layer 0: ks=bid>>2 (0..2), nt=bid&3, K=96
        int ks = bid >> 2, nt = bid & 3;
        int n = nt * 16 + c;
#pragma unroll
        for (int j = 0; j < 8; ++j) {
            int kg = ks * 32 + kbase + j;
            float v = (kg < 64) ? W0[(kg & 1) * 2048 + (kg >> 1) * 64 + n]
                                : R0[(kg - 64) * 64 + n];
            vals[j] = (_Float16)v;
        }
        *reinterpret_cast<f16x8*>(Bf0 + ((size_t)(bid * 64 + lane)) * 8) =
            *reinterpret_cast<f16x8*>(vals);
    } else if (bid < 36) {     // layer 1: t=bid-12, ks=t>>2 (0..5), nt=t&3, K=192
        int t = bid - 12;
        int ks = t >> 2, nt = t & 3;
        int n = nt * 16 + c;
#pragma unroll
        for (int j = 0; j < 8; ++j) {
            int kg = ks * 32 + kbase + j;
            float v = (kg < 128) ? W1[(kg & 1) * 4096 + (kg >> 1) * 64 + n]
                                 : R1[(kg - 128) * 64 + n];
            vals[j] = (_Float16)v;
        }
        *reinterpret_cast<f16x8*>(Bf1 + ((size_t)(t * 64 + lane)) * 8) =
            *reinterpret_cast<f16x8*>(vals);
    } else if (bid < 40) {     // layer 2: [Wa|Wb packed, R], 2 ks x 2 nt
        int ksnt = bid - 36;   // 0..3
        int ks = ksnt >> 1, nt = ksnt & 1;
#pragma unroll
        for (int j = 0; j < 8; ++j) {
            int k = ks * 32 + kbase + j;
            float v = 0.f;
            if (nt == 0) {
                if (c < 7)                 v = W2[k * 7 + c];
                else if (c >= 8 && c < 15) v = W2[448 + k * 7 + (c - 8)];
            } else {
                if (c < 7)                 v = R2[k * 7 + c];
            }
            vals[j] = (_Float16)v;
        }
        *reinterpret_cast<f16x8*>(Bf7 + ((size_t)(ksnt * 64 + lane)) * 8) =
            *reinterpret_cast<f16x8*>(vals);
    } else if (bid == 40) {    // fold BN0
        float s = G0[lane] * rsqrtf(RV0[lane] + EPSV);
        bn0[lane] = s;
        bn0[64 + lane] = B0[lane] * s + BE0[lane] - RM0[lane] * s;
    } else if (bid == 41) {    // fold BN1
        float s = G1[lane] * rsqrtf(RV1[lane] + EPSV);
        bn1[lane] = s;
        bn1[64 + lane] = B1[lane] * s + BE1[lane] - RM1[lane] * s;
    } else {                   // bucket cursor init
        int b = (bid - 42) * 64 + lane;
        if (b < NB) bcursor[b] = b * CAP;
    }
}

// ---------------- fused: binB (blocks 0..NB-1, 512 thr, 4 edges/thread) || x f32->f16 ----------------
__global__ __launch_bounds__(512) void binB_xh_kernel(
        const int* __restrict__ src, const int* __restrict__ dst,
        const float* __restrict__ attr, int* __restrict__ bcursor,
        uint2* __restrict__ es1, int E,
        const float* __restrict__ x, __half* __restrict__ xh) {
    __shared__ int hist[NB];
    __shared__ int base[NB];
    if (blockIdx.x >= NB) {    // x -> half, 8 floats/thread (512 thr -> 4096 floats/block)
        int t = (blockIdx.x - NB) * 512 + threadIdx.x;
        size_t idx = (size_t)t * 8;
        if (idx < (size_t)NN * 32) {
            float4 f0 = *reinterpret_cast<const float4*>(x + idx);
            float4 f1 = *reinterpret_cast<const float4*>(x + idx + 4);
            _Float16 v[8] = {(_Float16)f0.x, (_Float16)f0.y, (_Float16)f0.z, (_Float16)f0.w,
                             (_Float16)f1.x, (_Float16)f1.y, (_Float16)f1.z, (_Float16)f1.w};
            *reinterpret_cast<f16x8*>(xh + idx) = *reinterpret_cast<f16x8*>(v);
        }
        return;
    }
    for (int i = threadIdx.x; i < NB; i += blockDim.x) hist[i] = 0;
    __syncthreads();
    const int chunk = (E + NB - 1) / NB;   // 2046 -> 4 edges/thread at 512 thr
    int e0 = blockIdx.x * chunk;
    int e1 = e0 + chunk; if (e1 > E) e1 = E;
    unsigned su[4]; unsigned char dlv[4]; short bv[4];
#pragma unroll
    for (int j = 0; j < 4; ++j) {
        int e = e0 + threadIdx.x + j * 512;
        if (e < e1) {
            int d = dst[e];
            int b = d >> BSHIFT;
            __half uh = __float2half_rn(attr[e]);
            su[j]  = ((unsigned)src[e] << 16) | (unsigned)__half_as_ushort(uh);
            dlv[j] = (unsigned char)(d & (BSIZE - 1));
            bv[j]  = (short)b;
            atomicAdd(&hist[b], 1);
        }
    }
    __syncthreads();
    for (int i = threadIdx.x; i < NB; i += blockDim.x) {
        int cnt = hist[i];
        base[i] = cnt ? atomicAdd(&bcursor[i], cnt) : 0;
        hist[i] = 0;
    }
    __syncthreads();
#pragma unroll
    for (int j = 0; j < 4; ++j) {
        int e = e0 + threadIdx.x + j * 512;
        if (e < e1) {
            int b = bv[j];
            int slot = base[b] + atomicAdd(&hist[b], 1);
            uint2 rec; rec.x = su[j]; rec.y = (unsigned)dlv[j];
            es1[slot] = rec;       // single 8B store (one cache-line touch)
        }
    }
}

// ---------------- exact placement (512 thr, 5 slots/thread), node ranges PADDED to x16 ----------------
// rowrange[n] = { beg, (deg<<16) | padded }
__global__ __launch_bounds__(512) void placeC_kernel(const int* __restrict__ bcursor,
                                                     const uint2* __restrict__ es1,
                                                     int2* __restrict__ rowrange,
                                                     uint2* __restrict__ es8) {
    __shared__ int hist[BSIZE];
    __shared__ int stmp[BSIZE];
    __shared__ int cur[BSIZE];
    int b = blockIdx.x;
    int t = threadIdx.x;
    int bs = b * CAP;
    int be = bcursor[b];
    if (t < BSIZE) hist[t] = 0;
    __syncthreads();
    // pass 1: read edges ONCE into registers (5/thread covers 2560 >= max bucket load), count dst-locals
    unsigned su[5]; unsigned char dlv[5];
#pragma unroll
    for (int j = 0; j < 5; ++j) {
        int i = bs + t + j * 512;
        if (i < be) {
            uint2 r = es1[i];
            su[j]  = r.x;
            dlv[j] = (unsigned char)r.y;
            atomicAdd(&hist[dlv[j]], 1);
        }
    }
    __syncthreads();
    if (t < BSIZE) {
        int v = hist[t];
        int pv = (v + 15) & ~15;     // padded length
        int incl = pv;
#pragma unroll
        for (int o = 1; o < 64; o <<= 1) {
            int nv = __shfl_up(incl, o, 64);
            if ((t & 63) >= o) incl += nv;
        }
        stmp[t] = incl;
    }
    __syncthreads();
    if (t < BSIZE) {
        int v = hist[t];
        int pv = (v + 15) & ~15;
        int excl = stmp[t] - pv + ((t >= 64) ? stmp[63] : 0);
        cur[t] = excl;
        int node = b * BSIZE + t;
        if (node < NN) {
            int2 rr; rr.x = bs + excl; rr.y = (v << 16) | pv;
            rowrange[node] = rr;
        }
    }
    __syncthreads();
    // pass 2: place from registers, packing {src, half2(1-u,u)}
#pragma unroll
    for (int j = 0; j < 5; ++j) {
        int i = bs + t + j * 512;
        if (i < be) {
            unsigned r = su[j];
            int dl = dlv[j];
            int slot = bs + atomicAdd(&cur[dl], 1);
            __half uh = __ushort_as_half((unsigned short)(r & 0xffffu));
            __half2 p = __halves2half2(__hsub(__ushort_as_half((unsigned short)0x3C00u), uh), uh);
            uint2 rec;
            rec.x = r >> 16;
            rec.y = *reinterpret_cast<unsigned*>(&p);
            es8[slot] = rec;
        }
    }
    __syncthreads();
    // fill pad slots with zero-weight records ({src=0, u2=0} contributes exactly 0)
    if (t < BSIZE) {
        int v = hist[t];
        int pv = (v + 15) & ~15;
        int start = bs + cur[t];          // cur[t] == excl + v after pass 2
        int endp  = bs + (cur[t] - v) + pv;
        uint2 z; z.x = 0u; z.y = 0u;
        for (int k = start; k < endp; ++k) es8[k] = z;
    }
}

// ---------------- fused layer 0: gather(CIN=32, 4 nodes/wave) -> LDS -> wave-0 GEMM K=96 ----------------
// Block = 16 nodes (3125 blocks, NN = 3125*16 exactly). Rowranges preloaded (one coalesced load).
__global__ __launch_bounds__(256, 8) void gf0_kernel(const int2* __restrict__ rowrange,
                                                     const uint2* __restrict__ es8,
                                                     const __half* __restrict__ xh,
                                                     const __half* __restrict__ Bf0,
                                                     const float* __restrict__ bn,
                                                     __half* __restrict__ h0, int n_nodes) {
    __shared__ __align__(16) char ldsS[16 * 128];   // 16 rows x 64 halves, XOR-swizzled
    const int lane = threadIdx.x & 63;
    const int wid  = threadIdx.x >> 6;
    const int nb = blockIdx.x * 16;
    const unsigned c2 = (unsigned)((lane & 31) << 1);
    const char* xb = (const char*)xh;
    // preload this wave's 4 rowranges (lane&3 selects; same addr across groups -> broadcast)
    int2 rr4 = rowrange[nb + wid * 4 + (lane & 3)];
#pragma unroll 1
    for (int k = 0; k < 4; ++k) {
        int row = wid * 4 + k;
        int beg  = __builtin_amdgcn_readfirstlane(__shfl(rr4.x, k, 64));
        int meta = __builtin_amdgcn_readfirstlane(__shfl(rr4.y, k, 64));
        int end = beg + (meta & 0xffff);
        float a0 = 0.f, a1 = 0.f, a2 = 0.f, a3 = 0.f;
        float a4 = 0.f, a5 = 0.f, a6 = 0.f, a7 = 0.f;
        float b0 = 0.f, b1 = 0.f, b2 = 0.f, b3 = 0.f;
        float b4 = 0.f, b5 = 0.f, b6 = 0.f, b7 = 0.f;
        int i = beg + (lane >> 5);
        for (; i + 14 < end; i += 16) {     // exact: padded multiple of 16
            uint2 q0 = es8[i];
            uint2 q1 = es8[i + 2];
            uint2 q2 = es8[i + 4];
            uint2 q3 = es8[i + 6];
            uint2 q4 = es8[i + 8];
            uint2 q5 = es8[i + 10];
            uint2 q6 = es8[i + 12];
            uint2 q7 = es8[i + 14];
            __half x0 = *(const __half*)(xb + ((q0.x << 6) | c2));
            __half x1 = *(const __half*)(xb + ((q1.x << 6) | c2));
            __half x2 = *(const __half*)(xb + ((q2.x << 6) | c2));
            __half x3 = *(const __half*)(xb + ((q3.x << 6) | c2));
            __half x4 = *(const __half*)(xb + ((q4.x << 6) | c2));
            __half x5 = *(const __half*)(xb + ((q5.x << 6) | c2));
            __half x6 = *(const __half*)(xb + ((q6.x << 6) | c2));
            __half x7 = *(const __half*)(xb + ((q7.x << 6) | c2));
            __half2 u0 = __builtin_bit_cast(__half2, q0.y);
            __half2 u1 = __builtin_bit_cast(__half2, q1.y);
            __half2 u2 = __builtin_bit_cast(__half2, q2.y);
            __half2 u3 = __builtin_bit_cast(__half2, q3.y);
            __half2 u4 = __builtin_bit_cast(__half2, q4.y);
            __half2 u5 = __builtin_bit_cast(__half2, q5.y);
            __half2 u6 = __builtin_bit_cast(__half2, q6.y);
            __half2 u7 = __builtin_bit_cast(__half2, q7.y);
            float f0 = __half2float(x0), f1 = __half2float(x1);
            float f2 = __half2float(x2), f3 = __half2float(x3);
            float f4 = __half2float(x4), f5 = __half2float(x5);
            float f6 = __half2float(x6), f7 = __half2float(x7);
            a0 = fmaf(__low2float(u0), f0, a0); b0 = fmaf(__high2float(u0), f0, b0);
            a1 = fmaf(__low2float(u1), f1, a1); b1 = fmaf(__high2float(u1), f1, b1);
            a2 = fmaf(__low2float(u2), f2, a2); b2 = fmaf(__high2float(u2), f2, b2);
            a3 = fmaf(__low2float(u3), f3, a3); b3 = fmaf(__high2float(u3), f3, b3);
            a4 = fmaf(__low2float(u4), f4, a4); b4 = fmaf(__high2float(u4), f4, b4);
            a5 = fmaf(__low2float(u5), f5, a5); b5 = fmaf(__high2float(u5), f5, b5);
            a6 = fmaf(__low2float(u6), f6, a6); b6 = fmaf(__high2float(u6), f6, b6);
            a7 = fmaf(__low2float(u7), f7, a7); b7 = fmaf(__high2float(u7), f7, b7);
        }
        float a = ((a0 + a1) + (a2 + a3)) + ((a4 + a5) + (a6 + a7));
        float b = ((b0 + b1) + (b2 + b3)) + ((b4 + b5) + (b6 + b7));
        a += __shfl_xor(a, 32);
        b += __shfl_xor(b, 32);
        float degv = (float)(meta >> 16);
        if (degv < 1.f) degv = 1.f;
        float inv = 1.f / degv;
        if (lane < 32) {
            int byte = (row * 128 + (lane & 31) * 4) ^ ((row & 7) << 4);
            *reinterpret_cast<__half2*>(ldsS + byte) = __floats2half2_rn(a * inv, b * inv);
        }
    }
    __syncthreads();
    if (wid != 0) return;

    // ---- wave-0 GEMM: rows nb..nb+15, A=[S(LDS) | xh], K=96, N=64, BN+ELU -> h0 ----
    const int m0 = nb;
    f32x4 acc[4];
#pragma unroll
    for (int i = 0; i < 4; ++i) acc[i] = (f32x4){0.f, 0.f, 0.f, 0.f};
    const int rowl = lane & 15;
    const int g = lane >> 4;
    const int koff = g << 3;
    const int swz = (rowl & 7) << 4;
    const f16x8* bf = reinterpret_cast<const f16x8*>(Bf0);
    f16x8 a0v = *reinterpret_cast<const f16x8*>(ldsS + ((rowl * 128 + g * 16) ^ swz));
    f16x8 a1v = *reinterpret_cast<const f16x8*>(ldsS + ((rowl * 128 + 64 + g * 16) ^ swz));
    f16x8 a2v = *reinterpret_cast<const f16x8*>((const _Float16*)xh + (size_t)(m0 + rowl) * 32 + koff);
#pragma unroll
    for (int nt = 0; nt < 4; ++nt)
        acc[nt] = __builtin_amdgcn_mfma_f32_16x16x32_f16(a0v, bf[nt * 64 + lane], acc[nt], 0, 0, 0);
#pragma unroll
    for (int nt = 0; nt < 4; ++nt)
        acc[nt] = __builtin_amdgcn_mfma_f32_16x16x32_f16(a1v, bf[(4 + nt) * 64 + lane], acc[nt], 0, 0, 0);
#pragma unroll
    for (int nt = 0; nt < 4; ++nt)
        acc[nt] = __builtin_amdgcn_mfma_f32_16x16x32_f16(a2v, bf[(8 + nt) * 64 + lane], acc[nt], 0, 0, 0);
    const int c_lo  = lane & 15;
    const int rbase = ((lane >> 4) << 2);
#pragma unroll
    for (int nt = 0; nt < 4; ++nt) {
        int cc = nt * 16 + c_lo;
        float sc = bn[cc], sh = bn[64 + cc];
#pragma unroll
        for (int r = 0; r < 4; ++r) {
            int rw = m0 + rbase + r;
            float v = acc[nt][r] * sc + sh;
            v = v > 0.f ? v : expm1f(v);
            h0[(size_t)rw * 64 + cc] = __float2half(v);
        }
    }
}

// ---------------- fused layer 1+2: gather(CIN=64, 4 nodes/wave, 16-deep) -> LDS -> GEMM K=192 -> GEMM7 ----------------
__global__ __launch_bounds__(256, 8) void gf1_kernel(const int2* __restrict__ rowrange,
                                                     const uint2* __restrict__ es8,
                                                     const __half* __restrict__ h0,
                                                     const __half* __restrict__ Bf1,
                                                     const __half* __restrict__ Bf7,
                                                     const float* __restrict__ bn,
                                                     const float* __restrict__ Bb2,
                                                     __half* __restrict__ Yab7H,  // (n,8) half2{a,b}
                                                     float* __restrict__ Z7,      // (n,8)
                                                     int n_nodes) {
    __shared__ __align__(16) char ldsS[16 * 256];  // 16 rows x 128 halves (s0⋈s1), swizzled
    __shared__ __align__(16) char ldsH[16 * 128];  // 16 rows x 64 halves (h1), swizzled
    const int lane = threadIdx.x & 63;
    const int wid  = threadIdx.x >> 6;
    const int nb = blockIdx.x * 16;
    const unsigned c2 = (unsigned)(lane << 1);
    const char* xb = (const char*)h0;
    int2 rr4 = rowrange[nb + wid * 4 + (lane & 3)];
#pragma unroll 1
    for (int k = 0; k < 4; ++k) {
        int row = wid * 4 + k;
        int beg  = __builtin_amdgcn_readfirstlane(__shfl(rr4.x, k, 64));
        int meta = __builtin_amdgcn_readfirstlane(__shfl(rr4.y, k, 64));
        int end = beg + (meta & 0xffff);
        float a0 = 0.f, a1 = 0.f, a2 = 0.f, a3 = 0.f;
        float a4 = 0.f, a5 = 0.f, a6 = 0.f, a7 = 0.f;
        float b0 = 0.f, b1 = 0.f, b2 = 0.f, b3 = 0.f;
        float b4 = 0.f, b5 = 0.f, b6 = 0.f, b7 = 0.f;
        for (int i = beg; i + 15 < end; i += 16) {   // exact: padded multiple of 16
            uint4 p0 = *reinterpret_cast<const uint4*>(es8 + i);
            uint4 p1 = *reinterpret_cast<const uint4*>(es8 + i + 2);
            uint4 p2 = *reinterpret_cast<const uint4*>(es8 + i + 4);
            uint4 p3 = *reinterpret_cast<const uint4*>(es8 + i + 6);
            uint4 p4 = *reinterpret_cast<const uint4*>(es8 + i + 8);
            uint4 p5 = *reinterpret_cast<const uint4*>(es8 + i + 10);
            uint4 p6 = *reinterpret_cast<const uint4*>(es8 + i + 12);
            uint4 p7 = *reinterpret_cast<const uint4*>(es8 + i + 14);
            __half x0 = *(const __half*)(xb + ((p0.x << 7) | c2));
            __half x1 = *(const __half*)(xb + ((p0.z << 7) | c2));
            __half x2 = *(const __half*)(xb + ((p1.x << 7) | c2));
            __half x3 = *(const __half*)(xb + ((p1.z << 7) | c2));
            __half x4 = *(const __half*)(xb + ((p2.x << 7) | c2));
            __half x5 = *(const __half*)(xb + ((p2.z << 7) | c2));
            __half x6 = *(const __half*)(xb + ((p3.x << 7) | c2));
            __half x7 = *(const __half*)(xb + ((p3.z << 7) | c2));
            __half x8 = *(const __half*)(xb + ((p4.x << 7) | c2));
            __half x9 = *(const __half*)(xb + ((p4.z << 7) | c2));
            __half xa = *(const __half*)(xb + ((p5.x << 7) | c2));
            __half xc = *(const __half*)(xb + ((p5.z << 7) | c2));
            __half xd = *(const __half*)(xb + ((p6.x << 7) | c2));
            __half xe = *(const __half*)(xb + ((p6.z << 7) | c2));
            __half xf = *(const __half*)(xb + ((p7.x << 7) | c2));
            __half xg = *(const __half*)(xb + ((p7.z << 7) | c2));
            __half2 u0 = __builtin_bit_cast(__half2, p0.y);
            __half2 u1 = __builtin_bit_cast(__half2, p0.w);
            __half2 u2 = __builtin_bit_cast(__half2, p1.y);
            __half2 u3 = __builtin_bit_cast(__half2, p1.w);
            __half2 u4 = __builtin_bit_cast(__half2, p2.y);
            __half2 u5 = __builtin_bit_cast(__half2, p2.w);
            __half2 u6 = __builtin_bit_cast(__half2, p3.y);
            __half2 u7 = __builtin_bit_cast(__half2, p3.w);
            __half2 u8 = __builtin_bit_cast(__half2, p4.y);
            __half2 u9 = __builtin_bit_cast(__half2, p4.w);
            __half2 ua = __builtin_bit_cast(__half2, p5.y);
            __half2 uc = __builtin_bit_cast(__half2, p5.w);
            __half2 ud = __builtin_bit_cast(__half2, p6.y);
            __half2 ue = __builtin_bit_cast(__half2, p6.w);
            __half2 uf = __builtin_bit_cast(__half2, p7.y);
            __half2 ug = __builtin_bit_cast(__half2, p7.w);
            float f0 = __half2float(x0), f1 = __half2float(x1);
            float f2 = __half2float(x2), f3 = __half2float(x3);
            float f4 = __half2float(x4), f5 = __half2float(x5);
            float f6 = __half2float(x6), f7 = __half2float(x7);
            float f8 = __half2float(x8), f9 = __half2float(x9);
            float fa = __half2float(xa), fc = __half2float(xc);
            float fd = __half2float(xd), fe = __half2float(xe);
            float ff = __half2float(xf), fg = __half2float(xg);
            a0 = fmaf(__low2float(u0), f0, a0); b0 = fmaf(__high2float(u0), f0, b0);
            a1 = fmaf(__low2float(u1), f1, a1); b1 = fmaf(__high2float(u1), f1, b1);
            a2 = fmaf(__low2float(u2), f2, a2); b2 = fmaf(__high2float(u2), f2, b2);
            a3 = fmaf(__low2float(u3), f3, a3); b3 = fmaf(__high2float(u3), f3, b3);
            a4 = fmaf(__low2float(u4), f4, a4); b4 = fmaf(__high2float(u4), f4, b4);
            a5 = fmaf(__low2float(u5), f5, a5); b5 = fmaf(__high2float(u5), f5, b5);
            a6 = fmaf(__low2float(u6), f6, a6); b6 = fmaf(__high2float(u6), f6, b6);
            a7 = fmaf(__low2float(u7), f7, a7); b7 = fmaf(__high2float(u7), f7, b7);
            a0 = fmaf(__low2float(u8), f8, a0); b0 = fmaf(__high2float(u8), f8, b0);
            a1 = fmaf(__low2float(u9), f9, a1); b1 = fmaf(__high2float(u9), f9, b1);
            a2 = fmaf(__low2float(ua), fa, a2); b2 = fmaf(__high2float(ua), fa, b2);
            a3 = fmaf(__low2float(uc), fc, a3); b3 = fmaf(__high2float(uc), fc, b3);
            a4 = fmaf(__low2float(ud), fd, a4); b4 = fmaf(__high2float(ud), fd, b4);
            a5 = fmaf(__low2float(ue), fe, a5); b5 = fmaf(__high2float(ue), fe, b5);
            a6 = fmaf(__low2float(uf), ff, a6); b6 = fmaf(__high2float(uf), ff, b6);
            a7 = fmaf(__low2float(ug), fg, a7); b7 = fmaf(__high2float(ug), fg, b7);
        }
        float a = ((a0 + a1) + (a2 + a3)) + ((a4 + a5) + (a6 + a7));
        float b = ((b0 + b1) + (b2 + b3)) + ((b4 + b5) + (b6 + b7));
        float degv = (float)(meta >> 16);
        if (degv < 1.f) degv = 1.f;
        float inv = 1.f / degv;
        int byte = (row * 256 + lane * 4) ^ ((row & 7) << 4);
        *reinterpret_cast<__half2*>(ldsS + byte) = __floats2half2_rn(a * inv, b * inv);
    }
    __syncthreads();
    if (wid != 0) return;

    // ---- wave-0 GEMM1: K=192 ([S(LDS,128) | h0(64)]), N=64, BN+ELU -> LDS H ----
    const int m0 = nb;
    f32x4 acc[4];
#pragma unroll
    for (int i = 0; i < 4; ++i) acc[i] = (f32x4){0.f, 0.f, 0.f, 0.f};
    const int rowl = lane & 15;
    const int g = lane >> 4;
    const int koff = g << 3;
    const int swz = (rowl & 7) << 4;
    const f16x8* bf = reinterpret_cast<const f16x8*>(Bf1);
    const _Float16* hp = (const _Float16*)h0 + (size_t)(m0 + rowl) * 64 + koff;
#pragma unroll
    for (int ks = 0; ks < 6; ++ks) {
        f16x8 av;
        if (ks < 4) av = *reinterpret_cast<const f16x8*>(ldsS + ((rowl * 256 + ks * 64 + g * 16) ^ swz));
        else        av = *reinterpret_cast<const f16x8*>(hp + (ks - 4) * 32);
#pragma unroll
        for (int nt = 0; nt < 4; ++nt)
            acc[nt] = __builtin_amdgcn_mfma_f32_16x16x32_f16(av, bf[(ks * 4 + nt) * 64 + lane], acc[nt], 0, 0, 0);
    }
    const int c_lo  = lane & 15;
    const int rbase = ((lane >> 4) << 2);
#pragma unroll
    for (int nt = 0; nt < 4; ++nt) {
        int cc = nt * 16 + c_lo;
        float sc = bn[cc], sh = bn[64 + cc];
#pragma unroll
        for (int r = 0; r < 4; ++r) {
            float v = acc[nt][r] * sc + sh;
            v = v > 0.f ? v : expm1f(v);
            int rl = rbase + r;
            *reinterpret_cast<__half*>(ldsH + ((rl * 128 + cc * 2) ^ ((rl & 7) << 4))) = __float2half(v);
        }
    }

    // ---- GEMM7: K=64 from LDS H (same wave), [a|b packed | R] -> Yab7H, Z7 ----
    f32x4 acc7[2];
    acc7[0] = (f32x4){0.f, 0.f, 0.f, 0.f};
    acc7[1] = (f32x4){0.f, 0.f, 0.f, 0.f};
    const f16x8* bf7 = reinterpret_cast<const f16x8*>(Bf7);
#pragma unroll
    for (int ks = 0; ks < 2; ++ks) {
        f16x8 av = *reinterpret_cast<const f16x8*>(ldsH + ((rowl * 128 + ks * 64 + g * 16) ^ swz));
#pragma unroll
        for (int nt = 0; nt < 2; ++nt)
            acc7[nt] = __builtin_amdgcn_mfma_f32_16x16x32_f16(av, bf7[(ks * 2 + nt) * 64 + lane], acc7[nt], 0, 0, 0);
    }
#pragma unroll
    for (int r = 0; r < 4; ++r) {
        int rw = m0 + rbase + r;
        if (c_lo < 7) {
            Yab7H[((size_t)rw << 4) + 2 * c_lo] = __float2half(acc7[0][r]);
            Z7[((size_t)rw << 3) + c_lo] = acc7[1][r] + Bb2[c_lo];
        } else if (c_lo >= 8 && c_lo < 15) {
            Yab7H[((size_t)rw << 4) + 2 * (c_lo - 8) + 1] = __float2half(acc7[0][r]);
        }
    }
}

// ---------------- gather (C=7, padded 8) + log_softmax: 8 lanes/node, 8-deep, NO tail ----------------
__global__ void gather7_final_kernel(const int2* __restrict__ rowrange,
                                     const uint2* __restrict__ es8,
                                     const __half2* __restrict__ Yab7H,  // (n,8) half2{a,b}
                                     const float* __restrict__ Z7,       // (n,8)
                                     float* __restrict__ out, int n_nodes) {
    int t = blockIdx.x * blockDim.x + threadIdx.x;
    int n = t >> 3;
    int c = t & 7;
    if (n >= n_nodes) return;
    int2 rr = rowrange[n];
    int beg = rr.x;
    int end = beg + (rr.y & 0xffff);
    const unsigned c4 = (unsigned)(c << 2);
    const char* yb = (const char*)Yab7H;
    float acc0 = 0.f, acc1 = 0.f, acc2 = 0.f, acc3 = 0.f;
    if (c < 7) {
        for (int i = beg; i + 7 < end; i += 8) {   // exact: padded multiple of 16
            uint2 q0 = es8[i];
            uint2 q1 = es8[i + 1];
            uint2 q2 = es8[i + 2];
            uint2 q3 = es8[i + 3];
            uint2 q4 = es8[i + 4];
            uint2 q5 = es8[i + 5];
            uint2 q6 = es8[i + 6];
            uint2 q7 = es8[i + 7];
            __half2 v0 = *(const __half2*)(yb + ((q0.x << 5) | c4));
            __half2 v1 = *(const __half2*)(yb + ((q1.x << 5) | c4));
            __half2 v2 = *(const __half2*)(yb + ((q2.x << 5) | c4));
            __half2 v3 = *(const __half2*)(yb + ((q3.x << 5) | c4));
            __half2 v4 = *(const __half2*)(yb + ((q4.x << 5) | c4));
            __half2 v5 = *(const __half2*)(yb + ((q5.x << 5) | c4));
            __half2 v6 = *(const __half2*)(yb + ((q6.x << 5) | c4));
            __half2 v7 = *(const __half2*)(yb + ((q7.x << 5) | c4));
            acc0 = __builtin_amdgcn_fdot2(__builtin_bit_cast(h2f, v0), __builtin_bit_cast(h2f, q0.y), acc0, false);
            acc1 = __builtin_amdgcn_fdot2(__builtin_bit_cast(h2f, v1), __builtin_bit_cast(h2f, q1.y), acc1, false);
            acc2 = __builtin_amdgcn_fdot2(__builtin_bit_cast(h2f, v2), __builtin_bit_cast(h2f, q2.y), acc2, false);
            acc3 = __builtin_amdgcn_fdot2(__builtin_bit_cast(h2f, v3), __builtin_bit_cast(h2f, q3.y), acc3, false);
            acc0 = __builtin_amdgcn_fdot2(__builtin_bit_cast(h2f, v4), __builtin_bit_cast(h2f, q4.y), acc0, false);
            acc1 = __builtin_amdgcn_fdot2(__builtin_bit_cast(h2f, v5), __builtin_bit_cast(h2f, q5.y), acc1, false);
            acc2 = __builtin_amdgcn_fdot2(__builtin_bit_cast(h2f, v6), __builtin_bit_cast(h2f, q6.y), acc2, false);
            acc3 = __builtin_amdgcn_fdot2(__builtin_bit_cast(h2f, v7), __builtin_bit_cast(h2f, q7.y), acc3, false);
        }
    }
    float acc = (acc0 + acc1) + (acc2 + acc3);
    float degv = (float)(rr.y >> 16);
    if (degv < 1.f) degv = 1.f;
    float v = (c < 7) ? (acc / degv + Z7[(n << 3) + c]) : -1e30f;
    float m = v;
#pragma unroll
    for (int o = 1; o < 8; o <<= 1) m = fmaxf(m, __shfl_xor(m, o, 8));
    float ex = (c < 7) ? expf(v - m) : 0.f;
    float ssum = ex;
#pragma unroll
    for (int o = 1; o < 8; o <<= 1) ssum += __shfl_xor(ssum, o, 8);
    if (c < 7) out[n * 7 + c] = v - m - logf(ssum);
}

extern "C" void kernel_launch(void* const* d_in, const int* in_sizes, int n_in,
                              void* d_out, int out_size, void* d_ws, size_t ws_size,
                              hipStream_t stream) {
    const float* x    = (const float*)d_in[0];
    const int*   ei   = (const int*)d_in[1];
    const float* attr = (const float*)d_in[2];
    const float* W0 = (const float*)d_in[3];
    const float* R0 = (const float*)d_in[4];
    const float* B0 = (const float*)d_in[5];
    const float* W1 = (const float*)d_in[6];
    const float* R1 = (const float*)d_in[7];
    const float* B1 = (const float*)d_in[8];
    const float* W2 = (const float*)d_in[9];
    const float* R2 = (const float*)d_in[10];
    const float* B2 = (const float*)d_in[11];
    const float* G0  = (const float*)d_in[12];
    const float* BE0 = (const float*)d_in[13];
    const float* RM0 = (const float*)d_in[14];
    const float* RV0 = (const float*)d_in[15];
    const float* G1  = (const float*)d_in[16];
    const float* BE1 = (const float*)d_in[17];
    const float* RM1 = (const float*)d_in[18];
    const float* RV1 = (const float*)d_in[19];

    const int* src = ei;
    const int* dst = ei + NE;
    float* out = (float*)d_out;

    // workspace layout
    char* ws = (char*)d_ws;
    size_t off = 0;
    auto alloc = [&](size_t bytes) { char* p = ws + off; off += (bytes + 255) & ~size_t(255); return p; };
    int*    bcursor  = (int*)    alloc(NB * sizeof(int));
    int2*   rowrange = (int2*)   alloc((size_t)NN * sizeof(int2));
    uint2*  es1      = (uint2*)  alloc((size_t)NB * CAP * sizeof(uint2));
    uint2*  es8      = (uint2*)  alloc((size_t)NB * CAP * sizeof(uint2));
    __half* Bf0      = (__half*) alloc((size_t)12 * 64 * 8 * sizeof(__half));
    __half* Bf1      = (__half*) alloc((size_t)24 * 64 * 8 * sizeof(__half));
    __half* Bf7      = (__half*) alloc((size_t)4 * 64 * 8 * sizeof(__half));
    float*  bn0      = (float*)  alloc(128 * sizeof(float));
    float*  bn1      = (float*)  alloc(128 * sizeof(float));
    __half* xh       = (__half*) alloc((size_t)(NN + 64) * 32 * sizeof(__half));
    __half* h0       = (__half*) alloc((size_t)(NN + 64) * 64 * sizeof(__half));
    __half* Yab7H    = (__half*) alloc((size_t)NN * 16 * sizeof(__half));
    float*  Z7       = (float*)  alloc((size_t)NN * 8 * sizeof(float));

    const int B = 256;
    const int B2w = 512;
    const int gF    = (NN + 15) / 16;                       // 3125: fused 16-node blocks (exact)
    const int gN8   = (NN * 8 + B - 1) / B;                 // 1563
    const int gConv = ((NN * 32) + (B2w * 8) - 1) / (B2w * 8);  // 391: x->half at 512 thr x 8 floats
    const int gPrep = 42 + (NB + 63) / 64;                  // 49

    // ---- setup: weight prep (interleaved cat) + BN fold + cursor init ----
    prep_all_kernel<<<gPrep, 64, 0, stream>>>(W0, R0, W1, R1, W2, R2, B0, B1,
                                              G0, BE0, RM0, RV0, G1, BE1, RM1, RV1,
                                              Bf0, Bf1, Bf7, bn0, bn1, bcursor);

    // ---- binB (512 thr, 4 edges/thread) co-launched with x->half conversion ----
    binB_xh_kernel<<<NB + gConv, B2w, 0, stream>>>(src, dst, attr, bcursor, es1, NE, x, xh);

    // ---- exact placement (512 thr, 5 slots/thread) -> es8, rowrange ----
    placeC_kernel<<<NB, B2w, 0, stream>>>(bcursor, es1, rowrange, es8);

    // ---- layer 0: fused gather(4 nodes/wave) + wave-0 GEMM(K=96)+BN+ELU ----
    gf0_kernel<<<gF, B, 0, stream>>>(rowrange, es8, xh, Bf0, bn0, h0, NN);

    // ---- layer 1+2: fused gather(16-deep) + wave-0 GEMM(K=192)+BN+ELU -> LDS -> GEMM7(K=64) ----
    gf1_kernel<<<gF, B, 0, stream>>>(rowrange, es8, h0, Bf1, Bf7, bn1, B2, Yab7H, Z7, NN);

    // ---- final: gather C=7 + log_softmax ----
    gather7_final_kernel<<<gN8, B, 0, stream>>>(rowrange, es8, (const __half2*)Yab7H, Z7, out, NN);
}